// Round 5
// baseline (316.453 us; speedup 1.0000x reference)
//
#include <hip/hip_runtime.h>
#include <hip/hip_fp16.h>

#define B_ 256
#define N_ 192
#define D_ 512
#define E_ 1024
#define H_ 512
#define K_ 58
#define M_ (B_*K_)      // 14848 real rows
#define M2_ (B_*64)     // 16384 padded rows (64 per batch, rows 58-63 zero)

typedef _Float16 f16;
typedef _Float16 half8 __attribute__((ext_vector_type(8)));
typedef float floatx4 __attribute__((ext_vector_type(4)));

__device__ inline half8 cvt8(float4 f0, float4 f1) {
  half8 r;
  r[0]=(f16)f0.x; r[1]=(f16)f0.y; r[2]=(f16)f0.z; r[3]=(f16)f0.w;
  r[4]=(f16)f1.x; r[5]=(f16)f1.y; r[6]=(f16)f1.z; r[7]=(f16)f1.w;
  return r;
}

// ---------- setup: weight cvt + topk + gather + L2norm + stats-zero ---------
__global__ void setup_kernel(const float* __restrict__ Wfc, const float* __restrict__ W2,
                             const float* __restrict__ W1, const float* __restrict__ attn,
                             const float* __restrict__ emb,
                             f16* __restrict__ Wcat, f16* __restrict__ W1_16,
                             f16* __restrict__ A16, float* __restrict__ csum) {
  __shared__ float sv[N_];
  __shared__ int sidx[K_];
  __shared__ int cnt;
  int blk = blockIdx.x, t = threadIdx.x;
  if (blk < 512) {                      // Wcat = [Wfc;W2]: 1024x1024 f16
    int idx = (blk*256 + t)*8;
    int e = idx >> 10, c = idx & 1023;
    const float* src = (c < 512) ? (Wfc + (size_t)e*512 + c)
                                 : (W2  + (size_t)e*512 + (c-512));
    half8 o = cvt8(((const float4*)src)[0], ((const float4*)src)[1]);
    *(uint4*)(Wcat + idx) = *(uint4*)&o;
  } else if (blk < 640) {               // W1_16: 512x512 f16
    int idx = ((blk-512)*256 + t)*8;
    const float* src = W1 + idx;
    half8 o = cvt8(((const float4*)src)[0], ((const float4*)src)[1]);
    *(uint4*)(W1_16 + idx) = *(uint4*)&o;
  } else if (blk < 896) {               // topk + gather + L2norm for batch b
    int b = blk - 640;
    if (t == 0) cnt = 0;
    if (t < N_) sv[t] = attn[(size_t)b*193*193 + 1 + t];
    __syncthreads();
    if (t < N_) {
      float v = sv[t]; int rank = 0;
      for (int j = 0; j < N_; ++j) {
        float vj = sv[j];
        rank += (vj > v) || (vj == v && j < t);   // lax.top_k stable tie-break
      }
      if (rank < K_) sidx[atomicAdd(&cnt, 1)] = t;  // slot order irrelevant (max/BN invariant)
    }
    __syncthreads();
    int w = t >> 6, lane = t & 63;
    for (int slot = w; slot < 64; slot += 4) {
      f16* dst = A16 + ((size_t)b*64 + slot)*1024 + lane*8;
      if (slot < K_) {
        const float* src = emb + ((size_t)b*N_ + sidx[slot])*D_ + lane*8;
        float4 v0 = ((const float4*)src)[0];
        float4 v1 = ((const float4*)src)[1];
        float s = v0.x*v0.x + v0.y*v0.y + v0.z*v0.z + v0.w*v0.w
                + v1.x*v1.x + v1.y*v1.y + v1.z*v1.z + v1.w*v1.w;
        #pragma unroll
        for (int off = 32; off > 0; off >>= 1) s += __shfl_xor(s, off);
        float inv = 1.0f / (sqrtf(s) + 1e-8f);
        half8 o;
        o[0]=(f16)(v0.x*inv); o[1]=(f16)(v0.y*inv); o[2]=(f16)(v0.z*inv); o[3]=(f16)(v0.w*inv);
        o[4]=(f16)(v1.x*inv); o[5]=(f16)(v1.y*inv); o[6]=(f16)(v1.z*inv); o[7]=(f16)(v1.w*inv);
        *(uint4*)dst = *(uint4*)&o;
      } else {
        uint4 z; z.x=0u; z.y=0u; z.z=0u; z.w=0u;
        *(uint4*)dst = z;   // pad rows zero
      }
    }
  } else {                              // zero csum(512)+css(512), contiguous
    float4 z; z.x=0.f; z.y=0.f; z.z=0.f; z.w=0.f;
    ((float4*)csum)[t] = z;
  }
}

// ---------- gemm1: h = A16[:,0:512] @ W1_16^T + b1 -> A16 right half + stats -
// 128x128 tile, BK=64, VGPR-staged 1-deep pipeline, swizzled LDS (chunk^(row&7)).
__launch_bounds__(256)
__global__ void gemm1_kernel(const f16* __restrict__ A16, const f16* __restrict__ W1_16,
                             const float* __restrict__ b1, f16* __restrict__ Aout,
                             float* __restrict__ csum, float* __restrict__ css) {
  __shared__ f16 sA[128*64];
  __shared__ f16 sB[128*64];
  __shared__ float sSum[4][64], sSS[4][64];
  int t = threadIdx.x;
  int n0 = blockIdx.x * 128;
  int m0 = blockIdx.y * 128;
  int lane = t & 63, w = t >> 6, lm = lane & 15, quad = lane >> 4;
  int rh = w & 1, ch = w >> 1;
  int tr = t >> 3, tc = (t & 7) * 8;
  int wslot8 = ((t & 7) ^ (tr & 7)) * 8;
  floatx4 acc[4][4] = {};
  const f16* Ab = A16 + (size_t)m0*1024;       // left half (cols 0..511)
  const f16* Bb = W1_16 + (size_t)n0*512;
  uint4 rA[4], rB[4];
  #pragma unroll
  for (int i = 0; i < 4; ++i) {
    rA[i] = *(const uint4*)(Ab + (size_t)(i*32 + tr)*1024 + tc);
    rB[i] = *(const uint4*)(Bb + (size_t)(i*32 + tr)*512  + tc);
  }
  for (int it = 0; it < 8; ++it) {
    __syncthreads();
    #pragma unroll
    for (int i = 0; i < 4; ++i) {
      *(uint4*)&sA[(i*32 + tr)*64 + wslot8] = rA[i];
      *(uint4*)&sB[(i*32 + tr)*64 + wslot8] = rB[i];
    }
    __syncthreads();
    if (it < 7) {
      int kn = it*64 + 64;
      #pragma unroll
      for (int i = 0; i < 4; ++i) {
        rA[i] = *(const uint4*)(Ab + (size_t)(i*32 + tr)*1024 + kn + tc);
        rB[i] = *(const uint4*)(Bb + (size_t)(i*32 + tr)*512  + kn + tc);
      }
    }
    #pragma unroll
    for (int ksub = 0; ksub < 2; ++ksub) {
      int ko = ((quad + 4*ksub) ^ (lm & 7)) * 8;
      half8 a[4], bf[4];
      #pragma unroll
      for (int i = 0; i < 4; ++i) a[i]  = *(const half8*)&sA[(rh*64 + i*16 + lm)*64 + ko];
      #pragma unroll
      for (int j = 0; j < 4; ++j) bf[j] = *(const half8*)&sB[(ch*64 + j*16 + lm)*64 + ko];
      #pragma unroll
      for (int i = 0; i < 4; ++i)
        #pragma unroll
        for (int j = 0; j < 4; ++j)
          acc[i][j] = __builtin_amdgcn_mfma_f32_16x16x32_f16(a[i], bf[j], acc[i][j], 0, 0, 0);
    }
  }
  // epilogue: write pre-BN h into A16 right half, masked column stats
  #pragma unroll
  for (int j = 0; j < 4; ++j) {
    int col = n0 + ch*64 + j*16 + lm;
    float bias = b1[col];
    float s = 0.f, ss = 0.f;
    #pragma unroll
    for (int i = 0; i < 4; ++i) {
      int rib = i*16 + quad*4;          // row within batch (0..63)
      int row = m0 + rh*64 + rib;
      #pragma unroll
      for (int r = 0; r < 4; ++r) {
        float x = acc[i][j][r] + bias;
        Aout[(size_t)(row + r)*1024 + 512 + col] = (f16)x;
        if (rib + r < K_) { s += x; ss += x*x; }
      }
    }
    s  += __shfl_xor(s, 16);  s  += __shfl_xor(s, 32);
    ss += __shfl_xor(ss, 16); ss += __shfl_xor(ss, 32);
    if (lane < 16) { sSum[w][j*16 + lm] = s; sSS[w][j*16 + lm] = ss; }
  }
  __syncthreads();
  if (t < 128) {
    int wp = (t >> 6) * 2, ci = t & 63;
    atomicAdd(&csum[n0 + t], sSum[wp][ci] + sSum[wp+1][ci]);
    atomicAdd(&css[n0 + t],  sSS[wp][ci]  + sSS[wp+1][ci]);
  }
}

// ---------- fused: C = [base ; relu(bn(h))] @ Wcat^T, max over k, + biases ---
// BN+relu applied on the fly while staging A's right half; pad rows zeroed.
__launch_bounds__(256)
__global__ void fused_kernel(const f16* __restrict__ A16, const f16* __restrict__ Wcat,
                             const float* __restrict__ csum, const float* __restrict__ css,
                             const float* __restrict__ gamma, const float* __restrict__ beta,
                             const float* __restrict__ bfc, const float* __restrict__ b2,
                             float* __restrict__ out) {
  __shared__ f16 sA[128*64];
  __shared__ f16 sB[128*64];
  __shared__ float sSc[H_], sSh[H_];
  __shared__ float sMax[4][64];
  int t = threadIdx.x;
  int e0 = blockIdx.x * 128;
  int bm = blockIdx.y;                  // covers batches 2*bm, 2*bm+1
  int lane = t & 63, w = t >> 6, lm = lane & 15, quad = lane >> 4;
  int rh = w & 1, ch = w >> 1;
  int tr = t >> 3, tc = (t & 7) * 8;
  int wslot8 = ((t & 7) ^ (tr & 7)) * 8;
  // BN scale/shift (from gemm1's global stats)
  #pragma unroll
  for (int jj = 0; jj < 2; ++jj) {
    int j = t + jj*256;
    float mu  = csum[j] * (1.0f/M_);
    float var = css[j] * (1.0f/M_) - mu*mu;
    float sc  = gamma[j] * rsqrtf(var + 1e-5f);
    sSc[j] = sc;
    sSh[j] = beta[j] - mu*sc;
  }
  floatx4 acc[4][4] = {};
  const f16* Ab = A16 + (size_t)bm*128*1024;
  const f16* Bb = Wcat + (size_t)e0*1024;
  uint4 rA[4], rB[4];
  #pragma unroll
  for (int i = 0; i < 4; ++i) {
    rA[i] = *(const uint4*)(Ab + (size_t)(i*32 + tr)*1024 + tc);
    rB[i] = *(const uint4*)(Bb + (size_t)(i*32 + tr)*1024 + tc);
  }
  for (int it = 0; it < 16; ++it) {
    int k0 = it*64;
    __syncthreads();                    // also guards sSc/sSh on it==0
    if (k0 >= 512) {                    // right half: relu(bn(h)) on the fly
      int cb = k0 - 512 + tc;
      float4 sc0 = *(float4*)&sSc[cb], sc1 = *(float4*)&sSc[cb+4];
      float4 sh0 = *(float4*)&sSh[cb], sh1 = *(float4*)&sSh[cb+4];
      #pragma unroll
      for (int i = 0; i < 4; ++i) {
        half8 hv = *(half8*)&rA[i];
        half8 o;
        o[0]=(f16)fmaxf((float)hv[0]*sc0.x+sh0.x, 0.f);
        o[1]=(f16)fmaxf((float)hv[1]*sc0.y+sh0.y, 0.f);
        o[2]=(f16)fmaxf((float)hv[2]*sc0.z+sh0.z, 0.f);
        o[3]=(f16)fmaxf((float)hv[3]*sc0.w+sh0.w, 0.f);
        o[4]=(f16)fmaxf((float)hv[4]*sc1.x+sh1.x, 0.f);
        o[5]=(f16)fmaxf((float)hv[5]*sc1.y+sh1.y, 0.f);
        o[6]=(f16)fmaxf((float)hv[6]*sc1.z+sh1.z, 0.f);
        o[7]=(f16)fmaxf((float)hv[7]*sc1.w+sh1.w, 0.f);
        // pad rows (row_in_batch >= 58) must stage as zero: rows i*32+tr, batch = &63
        if ((i & 1) && ((t >> 3) >= 26)) { uint4 z; z.x=0u;z.y=0u;z.z=0u;z.w=0u; rA[i] = z; }
        else rA[i] = *(uint4*)&o;
      }
    }
    #pragma unroll
    for (int i = 0; i < 4; ++i) {
      *(uint4*)&sA[(i*32 + tr)*64 + wslot8] = rA[i];
      *(uint4*)&sB[(i*32 + tr)*64 + wslot8] = rB[i];
    }
    __syncthreads();
    if (it < 15) {
      int kn = k0 + 64;
      #pragma unroll
      for (int i = 0; i < 4; ++i) {
        rA[i] = *(const uint4*)(Ab + (size_t)(i*32 + tr)*1024 + kn + tc);
        rB[i] = *(const uint4*)(Bb + (size_t)(i*32 + tr)*1024 + kn + tc);
      }
    }
    #pragma unroll
    for (int ksub = 0; ksub < 2; ++ksub) {
      int ko = ((quad + 4*ksub) ^ (lm & 7)) * 8;
      half8 a[4], bf[4];
      #pragma unroll
      for (int i = 0; i < 4; ++i) a[i]  = *(const half8*)&sA[(rh*64 + i*16 + lm)*64 + ko];
      #pragma unroll
      for (int j = 0; j < 4; ++j) bf[j] = *(const half8*)&sB[(ch*64 + j*16 + lm)*64 + ko];
      #pragma unroll
      for (int i = 0; i < 4; ++i)
        #pragma unroll
        for (int j = 0; j < 4; ++j)
          acc[i][j] = __builtin_amdgcn_mfma_f32_16x16x32_f16(a[i], bf[j], acc[i][j], 0, 0, 0);
    }
  }
  // epilogue: masked max over the 58 real rows of this wave's batch (rh)
  #pragma unroll
  for (int j = 0; j < 4; ++j) {
    float mx = -3.0e38f;
    #pragma unroll
    for (int i = 0; i < 4; ++i) {
      int rib = i*16 + quad*4;
      #pragma unroll
      for (int r = 0; r < 4; ++r)
        if (rib + r < K_) mx = fmaxf(mx, acc[i][j][r]);
    }
    mx = fmaxf(mx, __shfl_xor(mx, 16));
    mx = fmaxf(mx, __shfl_xor(mx, 32));
    if (lane < 16) sMax[w][j*16 + lm] = mx;   // wave w: batch rh, cols ch*64+j*16+lm
  }
  __syncthreads();
  {
    int bb = t >> 7, c = t & 127;       // 2 batches x 128 cols
    float mx = sMax[(c >> 6)*2 + bb][c & 63];
    int e = e0 + c;
    out[((size_t)bm*2 + bb)*E_ + e] = mx + bfc[e] + b2[e];
  }
}

extern "C" void kernel_launch(void* const* d_in, const int* in_sizes, int n_in,
                              void* d_out, int out_size, void* d_ws, size_t ws_size,
                              hipStream_t stream) {
  const float* emb   = (const float*)d_in[0];
  const float* attn  = (const float*)d_in[1];
  const float* Wfc   = (const float*)d_in[2];
  const float* bfc   = (const float*)d_in[3];
  const float* W1    = (const float*)d_in[4];
  const float* b1    = (const float*)d_in[5];
  const float* gamma = (const float*)d_in[6];
  const float* beta  = (const float*)d_in[7];
  const float* W2    = (const float*)d_in[8];
  const float* b2    = (const float*)d_in[9];
  float* out = (float*)d_out;

  char* ws = (char*)d_ws;
  f16*   A16   = (f16*)(ws);                    // 16384*1024*2 = 33,554,432
  f16*   Wcat  = (f16*)(ws + 33554432);         // 1024*1024*2  =  2,097,152
  f16*   W1_16 = (f16*)(ws + 35651584);         //  512*512*2   =    524,288
  float* csum  = (float*)(ws + 36175872);       // 2048
  float* css   = (float*)(ws + 36177920);       // 2048 (contiguous after csum)

  setup_kernel<<<897, 256, 0, stream>>>(Wfc, W2, W1, attn, emb, Wcat, W1_16, A16, csum);
  gemm1_kernel<<<dim3(H_/128, M2_/128), 256, 0, stream>>>(A16, W1_16, b1, A16, csum, css);
  fused_kernel<<<dim3(E_/128, M2_/128), 256, 0, stream>>>(A16, Wcat, csum, css, gamma, beta,
                                                          bfc, b2, out);
}

// Round 6
// 249.882 us; speedup vs baseline: 1.2664x; 1.2664x over previous
//
#include <hip/hip_runtime.h>
#include <hip/hip_fp16.h>

#define B_ 256
#define N_ 192
#define D_ 512
#define E_ 1024
#define H_ 512
#define K_ 58
#define M_ (B_*K_)      // 14848 real rows
#define M2_ (B_*64)     // 16384 padded rows (64 per batch, rows 58-63 zero)

typedef _Float16 f16;
typedef unsigned int u32;
typedef _Float16 half8 __attribute__((ext_vector_type(8)));
typedef float floatx4 __attribute__((ext_vector_type(4)));

__device__ inline half8 cvt8(float4 f0, float4 f1) {
  half8 r;
  r[0]=(f16)f0.x; r[1]=(f16)f0.y; r[2]=(f16)f0.z; r[3]=(f16)f0.w;
  r[4]=(f16)f1.x; r[5]=(f16)f1.y; r[6]=(f16)f1.z; r[7]=(f16)f1.w;
  return r;
}

// async global->LDS, 16B/lane; LDS dest = wave-uniform base + lane*16
__device__ inline void gl_lds16(const f16* g, f16* l) {
  __builtin_amdgcn_global_load_lds((const __attribute__((address_space(1))) u32*)g,
                                   (__attribute__((address_space(3))) u32*)l, 16, 0, 0);
}

// Stage a 128x32 f16 tile with XOR swizzle: LDS slot (r, c') holds global
// chunk c = c' ^ ((r>>1)&3).  Lane l covers row l>>2, slot c'=l&3, fetching
// global chunk (l&3)^((l>>3)&3).  Conflict-free on MFMA-fragment read-back.
__device__ inline void stage128(const f16* gbase, int gstride, f16* sT, int w, int lane) {
  int lrow  = lane >> 2;
  int chunk = (lane & 3) ^ ((lane >> 3) & 3);
  gl_lds16(gbase + (size_t)(w*16      + lrow)*gstride + chunk*8, &sT[(w*16)*32]);
  gl_lds16(gbase + (size_t)(64 + w*16 + lrow)*gstride + chunk*8, &sT[(64 + w*16)*32]);
}

// ---------- setup: weight cvt + topk + gather + L2norm + stats-zero ---------
__global__ void setup_kernel(const float* __restrict__ Wfc, const float* __restrict__ W2,
                             const float* __restrict__ W1, const float* __restrict__ attn,
                             const float* __restrict__ emb,
                             f16* __restrict__ Wcat, f16* __restrict__ W1_16,
                             f16* __restrict__ A16, float* __restrict__ csum) {
  __shared__ float sv[N_];
  __shared__ int sidx[K_];
  __shared__ int cnt;
  int blk = blockIdx.x, t = threadIdx.x;
  if (blk < 512) {                      // Wcat = [Wfc;W2]: 1024x1024 f16
    int idx = (blk*256 + t)*8;
    int e = idx >> 10, c = idx & 1023;
    const float* src = (c < 512) ? (Wfc + (size_t)e*512 + c)
                                 : (W2  + (size_t)e*512 + (c-512));
    half8 o = cvt8(((const float4*)src)[0], ((const float4*)src)[1]);
    *(uint4*)(Wcat + idx) = *(uint4*)&o;
  } else if (blk < 640) {               // W1_16: 512x512 f16
    int idx = ((blk-512)*256 + t)*8;
    const float* src = W1 + idx;
    half8 o = cvt8(((const float4*)src)[0], ((const float4*)src)[1]);
    *(uint4*)(W1_16 + idx) = *(uint4*)&o;
  } else if (blk < 896) {               // topk + gather + L2norm for batch b
    int b = blk - 640;
    if (t == 0) cnt = 0;
    if (t < N_) sv[t] = attn[(size_t)b*193*193 + 1 + t];
    __syncthreads();
    if (t < N_) {
      float v = sv[t]; int rank = 0;
      for (int j = 0; j < N_; ++j) {
        float vj = sv[j];
        rank += (vj > v) || (vj == v && j < t);   // lax.top_k stable tie-break
      }
      if (rank < K_) sidx[atomicAdd(&cnt, 1)] = t;  // slot order irrelevant (max/BN invariant)
    }
    __syncthreads();
    int w = t >> 6, lane = t & 63;
    for (int slot = w; slot < 64; slot += 4) {
      f16* dst = A16 + ((size_t)b*64 + slot)*1024 + lane*8;
      if (slot < K_) {
        const float* src = emb + ((size_t)b*N_ + sidx[slot])*D_ + lane*8;
        float4 v0 = ((const float4*)src)[0];
        float4 v1 = ((const float4*)src)[1];
        float s = v0.x*v0.x + v0.y*v0.y + v0.z*v0.z + v0.w*v0.w
                + v1.x*v1.x + v1.y*v1.y + v1.z*v1.z + v1.w*v1.w;
        #pragma unroll
        for (int off = 32; off > 0; off >>= 1) s += __shfl_xor(s, off);
        float inv = 1.0f / (sqrtf(s) + 1e-8f);
        half8 o;
        o[0]=(f16)(v0.x*inv); o[1]=(f16)(v0.y*inv); o[2]=(f16)(v0.z*inv); o[3]=(f16)(v0.w*inv);
        o[4]=(f16)(v1.x*inv); o[5]=(f16)(v1.y*inv); o[6]=(f16)(v1.z*inv); o[7]=(f16)(v1.w*inv);
        *(uint4*)dst = *(uint4*)&o;
      } else {
        uint4 z; z.x=0u; z.y=0u; z.z=0u; z.w=0u;
        *(uint4*)dst = z;   // pad rows zero
      }
    }
  } else {                              // zero csum(512)+css(512), contiguous
    float4 z; z.x=0.f; z.y=0.f; z.z=0.f; z.w=0.f;
    ((float4*)csum)[t] = z;
  }
}

// ---------- gemm1: A16[:,512:1024] = A16[:,0:512] @ W1_16^T + b1 + stats ----
// 128x128 tile, BK=32, double-buffered LDS, ONE barrier per K-step.
__launch_bounds__(256)
__global__ void gemm1_kernel(const f16* __restrict__ A16, const f16* __restrict__ W1_16,
                             const float* __restrict__ b1, f16* __restrict__ Aout,
                             float* __restrict__ csum, float* __restrict__ css) {
  __shared__ f16 sA[2][128*32];
  __shared__ f16 sB[2][128*32];
  __shared__ float sSum[4][64], sSS[4][64];
  int t = threadIdx.x;
  int n0 = blockIdx.x * 128;
  int m0 = blockIdx.y * 128;
  int lane = t & 63, w = t >> 6, lm = lane & 15, quad = lane >> 4;
  int rh = w & 1, ch = w >> 1;          // wave -> (row-half, col-half)
  floatx4 acc[4][4] = {};
  const f16* Ab = A16 + (size_t)m0*1024;       // left half (cols 0..511)
  const f16* Bb = W1_16 + (size_t)n0*512;
  int sw = (quad ^ ((lm >> 1) & 3)) * 8;       // swizzled chunk offset for reads
  stage128(Ab, 1024, sA[0], w, lane);
  stage128(Bb, 512,  sB[0], w, lane);
  __syncthreads();                             // buf0 DMA complete
  for (int it = 0; it < 16; ++it) {
    int cur = it & 1, nxt = cur ^ 1;
    if (it < 15) {                             // DMA next tile, overlapped with compute
      stage128(Ab + (it+1)*32, 1024, sA[nxt], w, lane);
      stage128(Bb + (it+1)*32, 512,  sB[nxt], w, lane);
    }
    half8 a[4], bf[4];
    #pragma unroll
    for (int i = 0; i < 4; ++i) a[i]  = *(const half8*)&sA[cur][(rh*64 + i*16 + lm)*32 + sw];
    #pragma unroll
    for (int j = 0; j < 4; ++j) bf[j] = *(const half8*)&sB[cur][(ch*64 + j*16 + lm)*32 + sw];
    #pragma unroll
    for (int i = 0; i < 4; ++i)
      #pragma unroll
      for (int j = 0; j < 4; ++j)
        acc[i][j] = __builtin_amdgcn_mfma_f32_16x16x32_f16(a[i], bf[j], acc[i][j], 0, 0, 0);
    __syncthreads();                           // drains next-tile DMA after compute overlap
  }
  // epilogue: write pre-BN h into A16 right half, masked column stats
  #pragma unroll
  for (int j = 0; j < 4; ++j) {
    int col = n0 + ch*64 + j*16 + lm;
    float bias = b1[col];
    float s = 0.f, ss = 0.f;
    #pragma unroll
    for (int i = 0; i < 4; ++i) {
      int rib = i*16 + quad*4;          // row within batch (0..63)
      int row = m0 + rh*64 + rib;
      #pragma unroll
      for (int r = 0; r < 4; ++r) {
        float x = acc[i][j][r] + bias;
        Aout[(size_t)(row + r)*1024 + 512 + col] = (f16)x;
        if (rib + r < K_) { s += x; ss += x*x; }
      }
    }
    s  += __shfl_xor(s, 16);  s  += __shfl_xor(s, 32);
    ss += __shfl_xor(ss, 16); ss += __shfl_xor(ss, 32);
    if (lane < 16) { sSum[w][j*16 + lm] = s; sSS[w][j*16 + lm] = ss; }
  }
  __syncthreads();
  if (t < 128) {
    int wp = (t >> 6) * 2, ci = t & 63;
    atomicAdd(&csum[n0 + t], sSum[wp][ci] + sSum[wp+1][ci]);
    atomicAdd(&css[n0 + t],  sSS[wp][ci]  + sSS[wp+1][ci]);
  }
}

// ---------- bnrelu (in place on A16 right half): x -> relu(x*sc + sh) --------
__global__ void bnrelu_kernel(f16* __restrict__ A16, const float* __restrict__ csum,
                              const float* __restrict__ css, const float* __restrict__ gamma,
                              const float* __restrict__ beta) {
  __shared__ float sSc[H_], sSh[H_];
  int t = threadIdx.x;
  for (int j = t; j < H_; j += 256) {
    float mu  = csum[j] * (1.0f/M_);
    float var = css[j] * (1.0f/M_) - mu*mu;
    float sc  = gamma[j] * rsqrtf(var + 1e-5f);
    sSc[j] = sc;
    sSh[j] = beta[j] - mu*sc;
  }
  __syncthreads();
  int r0 = blockIdx.x * 16;
  #pragma unroll
  for (int i = 0; i < 4; ++i) {
    int seg = t + 256*i;                 // 16 rows x 64 col-segments
    int row = r0 + (seg >> 6);
    int c0  = (seg & 63) * 8;
    f16* p = A16 + (size_t)row*1024 + 512 + c0;
    if ((row & 63) >= K_) {
      uint4 z; z.x=0u; z.y=0u; z.z=0u; z.w=0u;
      *(uint4*)p = z;                    // pad rows must be zero (had +bias)
    } else {
      half8 hv = *(const half8*)p;
      half8 o;
      #pragma unroll
      for (int k = 0; k < 8; ++k)
        o[k] = (f16)fmaxf((float)hv[k]*sSc[c0+k] + sSh[c0+k], 0.0f);
      *(uint4*)p = *(uint4*)&o;
    }
  }
}

// ---------- fused: C = A16 @ Wcat^T, max over k per batch, + biases ----------
// 128x128 tile (2 batches), BK=32, double-buffered LDS, one barrier per step.
__launch_bounds__(256)
__global__ void fused_kernel(const f16* __restrict__ A16, const f16* __restrict__ Wcat,
                             const float* __restrict__ bfc, const float* __restrict__ b2,
                             float* __restrict__ out) {
  __shared__ f16 sA[2][128*32];
  __shared__ f16 sB[2][128*32];
  __shared__ float sMax[4][64];
  int t = threadIdx.x;
  int e0 = blockIdx.x * 128;
  int bm = blockIdx.y;                  // covers batches 2*bm, 2*bm+1
  int lane = t & 63, w = t >> 6, lm = lane & 15, quad = lane >> 4;
  int rh = w & 1, ch = w >> 1;
  floatx4 acc[4][4] = {};
  const f16* Ab = A16 + (size_t)bm*128*1024;
  const f16* Bb = Wcat + (size_t)e0*1024;
  int sw = (quad ^ ((lm >> 1) & 3)) * 8;
  stage128(Ab, 1024, sA[0], w, lane);
  stage128(Bb, 1024, sB[0], w, lane);
  __syncthreads();
  for (int it = 0; it < 32; ++it) {
    int cur = it & 1, nxt = cur ^ 1;
    if (it < 31) {
      stage128(Ab + (it+1)*32, 1024, sA[nxt], w, lane);
      stage128(Bb + (it+1)*32, 1024, sB[nxt], w, lane);
    }
    half8 a[4], bf[4];
    #pragma unroll
    for (int i = 0; i < 4; ++i) a[i]  = *(const half8*)&sA[cur][(rh*64 + i*16 + lm)*32 + sw];
    #pragma unroll
    for (int j = 0; j < 4; ++j) bf[j] = *(const half8*)&sB[cur][(ch*64 + j*16 + lm)*32 + sw];
    #pragma unroll
    for (int i = 0; i < 4; ++i)
      #pragma unroll
      for (int j = 0; j < 4; ++j)
        acc[i][j] = __builtin_amdgcn_mfma_f32_16x16x32_f16(a[i], bf[j], acc[i][j], 0, 0, 0);
    __syncthreads();
  }
  // epilogue: masked max over the 58 real rows of this wave's batch (rh)
  #pragma unroll
  for (int j = 0; j < 4; ++j) {
    float mx = -3.0e38f;
    #pragma unroll
    for (int i = 0; i < 4; ++i) {
      int rib = i*16 + quad*4;
      #pragma unroll
      for (int r = 0; r < 4; ++r)
        if (rib + r < K_) mx = fmaxf(mx, acc[i][j][r]);
    }
    mx = fmaxf(mx, __shfl_xor(mx, 16));
    mx = fmaxf(mx, __shfl_xor(mx, 32));
    if (lane < 16) sMax[w][j*16 + lm] = mx;   // wave w: batch rh, cols ch*64+j*16+lm
  }
  __syncthreads();
  {
    int bb = t >> 7, c = t & 127;       // 2 batches x 128 cols = 256 threads
    float mx = sMax[(c >> 6)*2 + bb][c & 63];
    int e = e0 + c;
    out[((size_t)bm*2 + bb)*E_ + e] = mx + bfc[e] + b2[e];
  }
}

extern "C" void kernel_launch(void* const* d_in, const int* in_sizes, int n_in,
                              void* d_out, int out_size, void* d_ws, size_t ws_size,
                              hipStream_t stream) {
  const float* emb   = (const float*)d_in[0];
  const float* attn  = (const float*)d_in[1];
  const float* Wfc   = (const float*)d_in[2];
  const float* bfc   = (const float*)d_in[3];
  const float* W1    = (const float*)d_in[4];
  const float* b1    = (const float*)d_in[5];
  const float* gamma = (const float*)d_in[6];
  const float* beta  = (const float*)d_in[7];
  const float* W2    = (const float*)d_in[8];
  const float* b2    = (const float*)d_in[9];
  float* out = (float*)d_out;

  char* ws = (char*)d_ws;
  f16*   A16   = (f16*)(ws);                    // 16384*1024*2 = 33,554,432
  f16*   Wcat  = (f16*)(ws + 33554432);         // 1024*1024*2  =  2,097,152
  f16*   W1_16 = (f16*)(ws + 35651584);         //  512*512*2   =    524,288
  float* csum  = (float*)(ws + 36175872);       // 2048
  float* css   = (float*)(ws + 36177920);       // 2048 (contiguous after csum)

  setup_kernel<<<897, 256, 0, stream>>>(Wfc, W2, W1, attn, emb, Wcat, W1_16, A16, csum);
  gemm1_kernel<<<dim3(H_/128, M2_/128), 256, 0, stream>>>(A16, W1_16, b1, A16, csum, css);
  bnrelu_kernel<<<M2_/16, 256, 0, stream>>>(A16, csum, css, gamma, beta);
  fused_kernel<<<dim3(E_/128, M2_/128), 256, 0, stream>>>(A16, Wcat, bfc, b2, out);
}

// Round 7
// 248.550 us; speedup vs baseline: 1.2732x; 1.0054x over previous
//
#include <hip/hip_runtime.h>
#include <hip/hip_fp16.h>

#define B_ 256
#define N_ 192
#define D_ 512
#define E_ 1024
#define H_ 512
#define K_ 58
#define M_ (B_*K_)      // 14848 real rows
#define M2_ (B_*64)     // 16384 padded rows (64 per batch, rows 58-63 zero)

typedef _Float16 f16;
typedef unsigned int u32;
typedef _Float16 half8 __attribute__((ext_vector_type(8)));
typedef float floatx4 __attribute__((ext_vector_type(4)));

__device__ inline half8 cvt8(float4 f0, float4 f1) {
  half8 r;
  r[0]=(f16)f0.x; r[1]=(f16)f0.y; r[2]=(f16)f0.z; r[3]=(f16)f0.w;
  r[4]=(f16)f1.x; r[5]=(f16)f1.y; r[6]=(f16)f1.z; r[7]=(f16)f1.w;
  return r;
}

// async global->LDS, 16B/lane; LDS dest = wave-uniform base + lane*16
__device__ inline void gl_lds16(const f16* g, f16* l) {
  __builtin_amdgcn_global_load_lds((const __attribute__((address_space(1))) u32*)g,
                                   (__attribute__((address_space(3))) u32*)l, 16, 0, 0);
}

// Stage Nx32 f16 tile with XOR swizzle: LDS slot (r, c') holds global chunk
// c = c' ^ ((r>>1)&3).  Lane l covers row l>>2, slot c'=l&3, fetching global
// chunk (l&3)^((l>>3)&3).  Conflict-free (2-way max) on MFMA fragment reads.
__device__ inline void stage128(const f16* gbase, int gstride, f16* sT, int w, int lane) {
  int lrow  = lane >> 2;
  int chunk = (lane & 3) ^ ((lane >> 3) & 3);
  gl_lds16(gbase + (size_t)(w*16      + lrow)*gstride + chunk*8, &sT[(w*16)*32]);
  gl_lds16(gbase + (size_t)(64 + w*16 + lrow)*gstride + chunk*8, &sT[(64 + w*16)*32]);
}
__device__ inline void stage256(const f16* gbase, int gstride, f16* sT, int w, int lane) {
  int lrow  = lane >> 2;
  int chunk = (lane & 3) ^ ((lane >> 3) & 3);
  #pragma unroll
  for (int q = 0; q < 4; ++q)
    gl_lds16(gbase + (size_t)(q*64 + w*16 + lrow)*gstride + chunk*8, &sT[(q*64 + w*16)*32]);
}

// ---------- setup: weight cvt + topk + gather + L2norm + stats-zero ---------
__global__ void setup_kernel(const float* __restrict__ Wfc, const float* __restrict__ W2,
                             const float* __restrict__ W1, const float* __restrict__ attn,
                             const float* __restrict__ emb,
                             f16* __restrict__ Wcat, f16* __restrict__ W1_16,
                             f16* __restrict__ A16, float* __restrict__ csum) {
  __shared__ float sv[N_];
  __shared__ int sidx[K_];
  __shared__ int cnt;
  int blk = blockIdx.x, t = threadIdx.x;
  if (blk < 512) {                      // Wcat = [Wfc;W2]: 1024x1024 f16
    int idx = (blk*256 + t)*8;
    int e = idx >> 10, c = idx & 1023;
    const float* src = (c < 512) ? (Wfc + (size_t)e*512 + c)
                                 : (W2  + (size_t)e*512 + (c-512));
    half8 o = cvt8(((const float4*)src)[0], ((const float4*)src)[1]);
    *(uint4*)(Wcat + idx) = *(uint4*)&o;
  } else if (blk < 640) {               // W1_16: 512x512 f16
    int idx = ((blk-512)*256 + t)*8;
    const float* src = W1 + idx;
    half8 o = cvt8(((const float4*)src)[0], ((const float4*)src)[1]);
    *(uint4*)(W1_16 + idx) = *(uint4*)&o;
  } else if (blk < 896) {               // topk + gather + L2norm for batch b
    int b = blk - 640;
    if (t == 0) cnt = 0;
    if (t < N_) sv[t] = attn[(size_t)b*193*193 + 1 + t];
    __syncthreads();
    if (t < N_) {
      float v = sv[t]; int rank = 0;
      for (int j = 0; j < N_; ++j) {
        float vj = sv[j];
        rank += (vj > v) || (vj == v && j < t);   // lax.top_k stable tie-break
      }
      if (rank < K_) sidx[atomicAdd(&cnt, 1)] = t;  // slot order irrelevant (max/BN invariant)
    }
    __syncthreads();
    int w = t >> 6, lane = t & 63;
    for (int slot = w; slot < 64; slot += 4) {
      f16* dst = A16 + ((size_t)b*64 + slot)*1024 + lane*8;
      if (slot < K_) {
        const float* src = emb + ((size_t)b*N_ + sidx[slot])*D_ + lane*8;
        float4 v0 = ((const float4*)src)[0];
        float4 v1 = ((const float4*)src)[1];
        float s = v0.x*v0.x + v0.y*v0.y + v0.z*v0.z + v0.w*v0.w
                + v1.x*v1.x + v1.y*v1.y + v1.z*v1.z + v1.w*v1.w;
        #pragma unroll
        for (int off = 32; off > 0; off >>= 1) s += __shfl_xor(s, off);
        float inv = 1.0f / (sqrtf(s) + 1e-8f);
        half8 o;
        o[0]=(f16)(v0.x*inv); o[1]=(f16)(v0.y*inv); o[2]=(f16)(v0.z*inv); o[3]=(f16)(v0.w*inv);
        o[4]=(f16)(v1.x*inv); o[5]=(f16)(v1.y*inv); o[6]=(f16)(v1.z*inv); o[7]=(f16)(v1.w*inv);
        *(uint4*)dst = *(uint4*)&o;
      } else {
        uint4 z; z.x=0u; z.y=0u; z.z=0u; z.w=0u;
        *(uint4*)dst = z;   // pad rows zero
      }
    }
  } else {                              // zero csum(512)+css(512), contiguous
    float4 z; z.x=0.f; z.y=0.f; z.z=0.f; z.w=0.f;
    ((float4*)csum)[t] = z;
  }
}

// ---------- gemm1: A16[:,512:1024] = A16[:,0:512] @ W1_16^T + b1 + stats ----
// 128x256 tile, BK=32, dbuf LDS, XCD-swizzled grid (256 blocks).
__launch_bounds__(256, 2)
__global__ void gemm1_kernel(const f16* __restrict__ A16, const f16* __restrict__ W1_16,
                             const float* __restrict__ b1, f16* __restrict__ Aout,
                             float* __restrict__ csum, float* __restrict__ css) {
  __shared__ f16 sA[2][128*32];
  __shared__ f16 sB[2][256*32];
  __shared__ float sSum[4][128], sSS[4][128];
  int t = threadIdx.x;
  int g = blockIdx.x;                   // 256 blocks: xcd-swizzled
  int xcd = g & 7, rest = g >> 3;
  int n0 = (rest & 1) * 256;
  int m  = xcd + 8*(rest >> 1);         // m-tile 0..127, same-m blocks same XCD
  int m0 = m * 128;
  int lane = t & 63, w = t >> 6, lm = lane & 15, quad = lane >> 4;
  int rw = w & 1, cw = w >> 1;          // wave -> 64-row half x 128-col half
  floatx4 acc[4][8] = {};
  const f16* Ab = A16 + (size_t)m0*1024;       // left half (cols 0..511)
  const f16* Bb = W1_16 + (size_t)n0*512;
  int sw = (quad ^ ((lm >> 1) & 3)) * 8;       // swizzled chunk offset for reads
  stage128(Ab, 1024, sA[0], w, lane);
  stage256(Bb, 512,  sB[0], w, lane);
  __syncthreads();
  for (int it = 0; it < 16; ++it) {
    int cur = it & 1, nxt = cur ^ 1;
    if (it < 15) {
      stage128(Ab + (it+1)*32, 1024, sA[nxt], w, lane);
      stage256(Bb + (it+1)*32, 512,  sB[nxt], w, lane);
    }
    half8 a[4], bf[8];
    #pragma unroll
    for (int i = 0; i < 4; ++i) a[i]  = *(const half8*)&sA[cur][(rw*64  + i*16 + lm)*32 + sw];
    #pragma unroll
    for (int j = 0; j < 8; ++j) bf[j] = *(const half8*)&sB[cur][(cw*128 + j*16 + lm)*32 + sw];
    #pragma unroll
    for (int i = 0; i < 4; ++i)
      #pragma unroll
      for (int j = 0; j < 8; ++j)
        acc[i][j] = __builtin_amdgcn_mfma_f32_16x16x32_f16(a[i], bf[j], acc[i][j], 0, 0, 0);
    __syncthreads();
  }
  // epilogue: write pre-BN h into A16 right half, masked column stats
  #pragma unroll
  for (int j = 0; j < 8; ++j) {
    int col = n0 + cw*128 + j*16 + lm;
    float bias = b1[col];
    float s = 0.f, ss = 0.f;
    #pragma unroll
    for (int i = 0; i < 4; ++i) {
      int rib = i*16 + quad*4;          // row within batch (0..63)
      int row = m0 + rw*64 + rib;
      #pragma unroll
      for (int r = 0; r < 4; ++r) {
        float x = acc[i][j][r] + bias;
        Aout[(size_t)(row + r)*1024 + 512 + col] = (f16)x;
        if (rib + r < K_) { s += x; ss += x*x; }
      }
    }
    s  += __shfl_xor(s, 16);  s  += __shfl_xor(s, 32);
    ss += __shfl_xor(ss, 16); ss += __shfl_xor(ss, 32);
    if (lane < 16) { sSum[w][j*16 + lm] = s; sSS[w][j*16 + lm] = ss; }
  }
  __syncthreads();
  {
    int c = t;                          // 256 cols in this block
    int w0 = 2*(c >> 7), ci = c & 127;  // waves rw=0/1 of this col-half
    atomicAdd(&csum[n0 + c], sSum[w0][ci] + sSum[w0+1][ci]);
    atomicAdd(&css[n0 + c],  sSS[w0][ci]  + sSS[w0+1][ci]);
  }
}

// ---------- bnrelu (in place on A16 right half): x -> relu(x*sc + sh) --------
__global__ void bnrelu_kernel(f16* __restrict__ A16, const float* __restrict__ csum,
                              const float* __restrict__ css, const float* __restrict__ gamma,
                              const float* __restrict__ beta) {
  __shared__ float sSc[H_], sSh[H_];
  int t = threadIdx.x;
  for (int j = t; j < H_; j += 256) {
    float mu  = csum[j] * (1.0f/M_);
    float var = css[j] * (1.0f/M_) - mu*mu;
    float sc  = gamma[j] * rsqrtf(var + 1e-5f);
    sSc[j] = sc;
    sSh[j] = beta[j] - mu*sc;
  }
  __syncthreads();
  int r0 = blockIdx.x * 16;
  #pragma unroll
  for (int i = 0; i < 4; ++i) {
    int seg = t + 256*i;                 // 16 rows x 64 col-segments
    int row = r0 + (seg >> 6);
    int c0  = (seg & 63) * 8;
    f16* p = A16 + (size_t)row*1024 + 512 + c0;
    if ((row & 63) >= K_) {
      uint4 z; z.x=0u; z.y=0u; z.z=0u; z.w=0u;
      *(uint4*)p = z;                    // pad rows must be zero (had +bias)
    } else {
      half8 hv = *(const half8*)p;
      half8 o;
      #pragma unroll
      for (int k = 0; k < 8; ++k)
        o[k] = (f16)fmaxf((float)hv[k]*sSc[c0+k] + sSh[c0+k], 0.0f);
      *(uint4*)p = *(uint4*)&o;
    }
  }
}

// ---------- fused: C = A16 @ Wcat^T, max over k per batch, + biases ----------
// 128x256 tile (2 batches x 256 e), BK=32, dbuf, XCD-swizzled grid (512 blocks).
__launch_bounds__(256, 2)
__global__ void fused_kernel(const f16* __restrict__ A16, const f16* __restrict__ Wcat,
                             const float* __restrict__ bfc, const float* __restrict__ b2,
                             float* __restrict__ out) {
  __shared__ f16 sA[2][128*32];
  __shared__ f16 sB[2][256*32];
  __shared__ float sMax[4][128];
  int t = threadIdx.x;
  int g = blockIdx.x;                   // 512 blocks: xcd-swizzled
  int xcd = g & 7, rest = g >> 3;
  int e0 = (rest & 3) * 256;
  int bm = xcd + 8*(rest >> 2);         // batch-pair 0..127; same-bm blocks same XCD
  int lane = t & 63, w = t >> 6, lm = lane & 15, quad = lane >> 4;
  int rw = w & 1, cw = w >> 1;
  floatx4 acc[4][8] = {};
  const f16* Ab = A16 + (size_t)bm*128*1024;
  const f16* Bb = Wcat + (size_t)e0*1024;
  int sw = (quad ^ ((lm >> 1) & 3)) * 8;
  stage128(Ab, 1024, sA[0], w, lane);
  stage256(Bb, 1024, sB[0], w, lane);
  __syncthreads();
  for (int it = 0; it < 32; ++it) {
    int cur = it & 1, nxt = cur ^ 1;
    if (it < 31) {
      stage128(Ab + (it+1)*32, 1024, sA[nxt], w, lane);
      stage256(Bb + (it+1)*32, 1024, sB[nxt], w, lane);
    }
    half8 a[4], bf[8];
    #pragma unroll
    for (int i = 0; i < 4; ++i) a[i]  = *(const half8*)&sA[cur][(rw*64  + i*16 + lm)*32 + sw];
    #pragma unroll
    for (int j = 0; j < 8; ++j) bf[j] = *(const half8*)&sB[cur][(cw*128 + j*16 + lm)*32 + sw];
    #pragma unroll
    for (int i = 0; i < 4; ++i)
      #pragma unroll
      for (int j = 0; j < 8; ++j)
        acc[i][j] = __builtin_amdgcn_mfma_f32_16x16x32_f16(a[i], bf[j], acc[i][j], 0, 0, 0);
    __syncthreads();
  }
  // epilogue: masked max over the 58 real rows of this wave's batch (rw)
  #pragma unroll
  for (int j = 0; j < 8; ++j) {
    float mx = -3.0e38f;
    #pragma unroll
    for (int i = 0; i < 4; ++i) {
      int rib = i*16 + quad*4;
      #pragma unroll
      for (int r = 0; r < 4; ++r)
        if (rib + r < K_) mx = fmaxf(mx, acc[i][j][r]);
    }
    mx = fmaxf(mx, __shfl_xor(mx, 16));
    mx = fmaxf(mx, __shfl_xor(mx, 32));
    if (lane < 16) sMax[w][j*16 + lm] = mx;   // wave w: batch rw, col-half cw
  }
  __syncthreads();
  #pragma unroll
  for (int bb = 0; bb < 2; ++bb) {
    int c = t;                           // 256 cols
    float mx = sMax[bb + 2*(c >> 7)][c & 127];
    int e = e0 + c;
    out[((size_t)bm*2 + bb)*E_ + e] = mx + bfc[e] + b2[e];
  }
}

extern "C" void kernel_launch(void* const* d_in, const int* in_sizes, int n_in,
                              void* d_out, int out_size, void* d_ws, size_t ws_size,
                              hipStream_t stream) {
  const float* emb   = (const float*)d_in[0];
  const float* attn  = (const float*)d_in[1];
  const float* Wfc   = (const float*)d_in[2];
  const float* bfc   = (const float*)d_in[3];
  const float* W1    = (const float*)d_in[4];
  const float* b1    = (const float*)d_in[5];
  const float* gamma = (const float*)d_in[6];
  const float* beta  = (const float*)d_in[7];
  const float* W2    = (const float*)d_in[8];
  const float* b2    = (const float*)d_in[9];
  float* out = (float*)d_out;

  char* ws = (char*)d_ws;
  f16*   A16   = (f16*)(ws);                    // 16384*1024*2 = 33,554,432
  f16*   Wcat  = (f16*)(ws + 33554432);         // 1024*1024*2  =  2,097,152
  f16*   W1_16 = (f16*)(ws + 35651584);         //  512*512*2   =    524,288
  float* csum  = (float*)(ws + 36175872);       // 2048
  float* css   = (float*)(ws + 36177920);       // 2048 (contiguous after csum)

  setup_kernel<<<897, 256, 0, stream>>>(Wfc, W2, W1, attn, emb, Wcat, W1_16, A16, csum);
  gemm1_kernel<<<256, 256, 0, stream>>>(A16, W1_16, b1, A16, csum, css);
  bnrelu_kernel<<<M2_/16, 256, 0, stream>>>(A16, csum, css, gamma, beta);
  fused_kernel<<<512, 256, 0, stream>>>(A16, Wcat, bfc, b2, out);
}

// Round 8
// 243.424 us; speedup vs baseline: 1.3000x; 1.0211x over previous
//
#include <hip/hip_runtime.h>
#include <hip/hip_fp16.h>

#define B_ 256
#define N_ 192
#define D_ 512
#define E_ 1024
#define H_ 512
#define K_ 58
#define M_ (B_*K_)      // 14848 real rows
#define M2_ (B_*64)     // 16384 padded rows (64 per batch, rows 58-63 zero)

typedef _Float16 f16;
typedef unsigned int u32;
typedef _Float16 half8 __attribute__((ext_vector_type(8)));
typedef float floatx4 __attribute__((ext_vector_type(4)));

__device__ inline half8 cvt8(float4 f0, float4 f1) {
  half8 r;
  r[0]=(f16)f0.x; r[1]=(f16)f0.y; r[2]=(f16)f0.z; r[3]=(f16)f0.w;
  r[4]=(f16)f1.x; r[5]=(f16)f1.y; r[6]=(f16)f1.z; r[7]=(f16)f1.w;
  return r;
}

// async global->LDS, 16B/lane; LDS dest = wave-uniform base + lane*16
__device__ inline void gl_lds16(const f16* g, f16* l) {
  __builtin_amdgcn_global_load_lds((const __attribute__((address_space(1))) u32*)g,
                                   (__attribute__((address_space(3))) u32*)l, 16, 0, 0);
}

// Stage Nx32 f16 tile with XOR swizzle: LDS slot (r, c') holds global chunk
// c = c' ^ ((r>>1)&3).  Lane l covers row l>>2, slot c'=l&3, fetching global
// chunk (l&3)^((l>>3)&3).  Conflict-free (2-way max) on MFMA fragment reads.
__device__ inline void stage128(const f16* gbase, int gstride, f16* sT, int w, int lane) {
  int lrow  = lane >> 2;
  int chunk = (lane & 3) ^ ((lane >> 3) & 3);
  gl_lds16(gbase + (size_t)(w*16      + lrow)*gstride + chunk*8, &sT[(w*16)*32]);
  gl_lds16(gbase + (size_t)(64 + w*16 + lrow)*gstride + chunk*8, &sT[(64 + w*16)*32]);
}
__device__ inline void stage256(const f16* gbase, int gstride, f16* sT, int w, int lane) {
  int lrow  = lane >> 2;
  int chunk = (lane & 3) ^ ((lane >> 3) & 3);
  #pragma unroll
  for (int q = 0; q < 4; ++q)
    gl_lds16(gbase + (size_t)(q*64 + w*16 + lrow)*gstride + chunk*8, &sT[(q*64 + w*16)*32]);
}

// ---------- setup: weight cvt + topk + gather + L2norm + stats-zero ---------
__global__ void setup_kernel(const float* __restrict__ Wfc, const float* __restrict__ W2,
                             const float* __restrict__ W1, const float* __restrict__ attn,
                             const float* __restrict__ emb,
                             f16* __restrict__ Wcat, f16* __restrict__ W1_16,
                             f16* __restrict__ A16, float* __restrict__ csum) {
  __shared__ float sv[N_];
  __shared__ int sidx[K_];
  __shared__ int cnt;
  int blk = blockIdx.x, t = threadIdx.x;
  if (blk < 512) {                      // Wcat = [Wfc;W2]: 1024x1024 f16
    int idx = (blk*256 + t)*8;
    int e = idx >> 10, c = idx & 1023;
    const float* src = (c < 512) ? (Wfc + (size_t)e*512 + c)
                                 : (W2  + (size_t)e*512 + (c-512));
    half8 o = cvt8(((const float4*)src)[0], ((const float4*)src)[1]);
    *(uint4*)(Wcat + idx) = *(uint4*)&o;
  } else if (blk < 640) {               // W1_16: 512x512 f16
    int idx = ((blk-512)*256 + t)*8;
    const float* src = W1 + idx;
    half8 o = cvt8(((const float4*)src)[0], ((const float4*)src)[1]);
    *(uint4*)(W1_16 + idx) = *(uint4*)&o;
  } else if (blk < 896) {               // topk + gather + L2norm for batch b
    int b = blk - 640;
    if (t == 0) cnt = 0;
    if (t < N_) sv[t] = attn[(size_t)b*193*193 + 1 + t];
    __syncthreads();
    if (t < N_) {
      float v = sv[t]; int rank = 0;
      for (int j = 0; j < N_; ++j) {
        float vj = sv[j];
        rank += (vj > v) || (vj == v && j < t);   // lax.top_k stable tie-break
      }
      if (rank < K_) sidx[atomicAdd(&cnt, 1)] = t;  // slot order irrelevant (max/BN invariant)
    }
    __syncthreads();
    int w = t >> 6, lane = t & 63;
    for (int slot = w; slot < 64; slot += 4) {
      f16* dst = A16 + ((size_t)b*64 + slot)*1024 + lane*8;
      if (slot < K_) {
        const float* src = emb + ((size_t)b*N_ + sidx[slot])*D_ + lane*8;
        float4 v0 = ((const float4*)src)[0];
        float4 v1 = ((const float4*)src)[1];
        float s = v0.x*v0.x + v0.y*v0.y + v0.z*v0.z + v0.w*v0.w
                + v1.x*v1.x + v1.y*v1.y + v1.z*v1.z + v1.w*v1.w;
        #pragma unroll
        for (int off = 32; off > 0; off >>= 1) s += __shfl_xor(s, off);
        float inv = 1.0f / (sqrtf(s) + 1e-8f);
        half8 o;
        o[0]=(f16)(v0.x*inv); o[1]=(f16)(v0.y*inv); o[2]=(f16)(v0.z*inv); o[3]=(f16)(v0.w*inv);
        o[4]=(f16)(v1.x*inv); o[5]=(f16)(v1.y*inv); o[6]=(f16)(v1.z*inv); o[7]=(f16)(v1.w*inv);
        *(uint4*)dst = *(uint4*)&o;
      } else {
        uint4 z; z.x=0u; z.y=0u; z.z=0u; z.w=0u;
        *(uint4*)dst = z;   // pad rows zero
      }
    }
  } else {                              // zero csum(512)+css(512), contiguous
    float4 z; z.x=0.f; z.y=0.f; z.z=0.f; z.w=0.f;
    ((float4*)csum)[t] = z;
  }
}

// ---------- gemm1: A16[:,512:1024] = A16[:,0:512] @ W1_16^T + b1 + stats ----
// 128x256 tile, BK=32, dbuf LDS, XCD-swizzled grid (256 blocks).
__launch_bounds__(256, 2)
__global__ void gemm1_kernel(const f16* __restrict__ A16, const f16* __restrict__ W1_16,
                             const float* __restrict__ b1, f16* __restrict__ Aout,
                             float* __restrict__ csum, float* __restrict__ css) {
  __shared__ f16 sA[2][128*32];
  __shared__ f16 sB[2][256*32];
  __shared__ float sSum[4][128], sSS[4][128];
  int t = threadIdx.x;
  int g = blockIdx.x;                   // 256 blocks: xcd-swizzled
  int xcd = g & 7, rest = g >> 3;
  int n0 = (rest & 1) * 256;
  int m  = xcd + 8*(rest >> 1);         // m-tile 0..127, same-m blocks same XCD
  int m0 = m * 128;
  int lane = t & 63, w = t >> 6, lm = lane & 15, quad = lane >> 4;
  int rw = w & 1, cw = w >> 1;          // wave -> 64-row half x 128-col half
  floatx4 acc[4][8] = {};
  const f16* Ab = A16 + (size_t)m0*1024;       // left half (cols 0..511)
  const f16* Bb = W1_16 + (size_t)n0*512;
  int sw = (quad ^ ((lm >> 1) & 3)) * 8;       // swizzled chunk offset for reads
  stage128(Ab, 1024, sA[0], w, lane);
  stage256(Bb, 512,  sB[0], w, lane);
  __syncthreads();
  for (int it = 0; it < 16; ++it) {
    int cur = it & 1, nxt = cur ^ 1;
    if (it < 15) {
      stage128(Ab + (it+1)*32, 1024, sA[nxt], w, lane);
      stage256(Bb + (it+1)*32, 512,  sB[nxt], w, lane);
    }
    half8 a[4], bf[8];
    #pragma unroll
    for (int i = 0; i < 4; ++i) a[i]  = *(const half8*)&sA[cur][(rw*64  + i*16 + lm)*32 + sw];
    #pragma unroll
    for (int j = 0; j < 8; ++j) bf[j] = *(const half8*)&sB[cur][(cw*128 + j*16 + lm)*32 + sw];
    #pragma unroll
    for (int i = 0; i < 4; ++i)
      #pragma unroll
      for (int j = 0; j < 8; ++j)
        acc[i][j] = __builtin_amdgcn_mfma_f32_16x16x32_f16(a[i], bf[j], acc[i][j], 0, 0, 0);
    __syncthreads();
  }
  // epilogue: write pre-BN h into A16 right half, masked column stats
  #pragma unroll
  for (int j = 0; j < 8; ++j) {
    int col = n0 + cw*128 + j*16 + lm;
    float bias = b1[col];
    float s = 0.f, ss = 0.f;
    #pragma unroll
    for (int i = 0; i < 4; ++i) {
      int rib = i*16 + quad*4;          // row within batch (0..63)
      int row = m0 + rw*64 + rib;
      #pragma unroll
      for (int r = 0; r < 4; ++r) {
        float x = acc[i][j][r] + bias;
        Aout[(size_t)(row + r)*1024 + 512 + col] = (f16)x;
        if (rib + r < K_) { s += x; ss += x*x; }
      }
    }
    s  += __shfl_xor(s, 16);  s  += __shfl_xor(s, 32);
    ss += __shfl_xor(ss, 16); ss += __shfl_xor(ss, 32);
    if (lane < 16) { sSum[w][j*16 + lm] = s; sSS[w][j*16 + lm] = ss; }
  }
  __syncthreads();
  {
    int c = t;                          // 256 cols in this block
    int w0 = 2*(c >> 7), ci = c & 127;  // waves rw=0/1 of this col-half
    atomicAdd(&csum[n0 + c], sSum[w0][ci] + sSum[w0+1][ci]);
    atomicAdd(&css[n0 + c],  sSS[w0][ci]  + sSS[w0+1][ci]);
  }
}

// ---------- fused: C = [base ; relu(bn(h))] @ Wcat^T, max over k, + biases ---
// 128x256 tile (2 batches x 256 e), BK=32, dbuf, XCD-swizzled grid.
// A left half + B: global_load_lds.  A right half: regs -> BN+relu -> ds_write
// (same XOR-swizzled layout; pad rows zeroed at stage time).
__launch_bounds__(256, 2)
__global__ void fused_kernel(const f16* __restrict__ A16, const f16* __restrict__ Wcat,
                             const float* __restrict__ csum, const float* __restrict__ css,
                             const float* __restrict__ gamma, const float* __restrict__ beta,
                             const float* __restrict__ bfc, const float* __restrict__ b2,
                             float* __restrict__ out) {
  __shared__ f16 sA[2][128*32];
  __shared__ f16 sB[2][256*32];
  __shared__ float sSc[H_], sSh[H_];
  __shared__ float sMax[4][128];
  int t = threadIdx.x;
  int g = blockIdx.x;                   // 512 blocks: xcd-swizzled
  int xcd = g & 7, rest = g >> 3;
  int e0 = (rest & 3) * 256;
  int bm = xcd + 8*(rest >> 2);         // batch-pair 0..127; same-bm blocks same XCD
  int lane = t & 63, w = t >> 6, lm = lane & 15, quad = lane >> 4;
  int rw = w & 1, cw = w >> 1;
  // BN scale/shift from gemm1's global stats
  #pragma unroll
  for (int jj = 0; jj < 2; ++jj) {
    int j = t + jj*256;
    float mu  = csum[j] * (1.0f/M_);
    float var = css[j] * (1.0f/M_) - mu*mu;
    float sc  = gamma[j] * rsqrtf(var + 1e-5f);
    sSc[j] = sc;
    sSh[j] = beta[j] - mu*sc;
  }
  floatx4 acc[4][8] = {};
  const f16* Ab = A16 + (size_t)bm*128*1024;
  const f16* Bb = Wcat + (size_t)e0*1024;
  int sw = (quad ^ ((lm >> 1) & 3)) * 8;
  // reg-path (A right half) constants: thread t covers rows t>>2 and 64+(t>>2),
  // LDS slot c'=t&3, global chunk (t&3)^((t>>3)&3)  [slot holds chunk c'^((r>>1)&3)]
  int rr = t >> 2;
  int rslot  = (t & 3) * 8;
  int rchunk = (t & 3) ^ ((t >> 3) & 3);
  bool pad = (rr >= K_);
  stage128(Ab, 1024, sA[0], w, lane);
  stage256(Bb, 1024, sB[0], w, lane);
  __syncthreads();                      // also guards sSc/sSh
  for (int it = 0; it < 32; ++it) {
    int cur = it & 1, nxt = cur ^ 1;
    int kn = (it + 1) * 32;
    uint4 h0, h1;
    bool regp = false;
    if (it < 31) {
      stage256(Bb + kn, 1024, sB[nxt], w, lane);
      if (kn < 512) {
        stage128(Ab + kn, 1024, sA[nxt], w, lane);
      } else {                          // plain loads now; BN+ds_write after compute
        regp = true;
        const f16* hp = Ab + (size_t)rr*1024 + kn + rchunk*8;
        h0 = *(const uint4*)hp;
        h1 = *(const uint4*)(hp + (size_t)64*1024);
      }
    }
    half8 a[4], bf[8];
    #pragma unroll
    for (int i = 0; i < 4; ++i) a[i]  = *(const half8*)&sA[cur][(rw*64  + i*16 + lm)*32 + sw];
    #pragma unroll
    for (int j = 0; j < 8; ++j) bf[j] = *(const half8*)&sB[cur][(cw*128 + j*16 + lm)*32 + sw];
    #pragma unroll
    for (int i = 0; i < 4; ++i)
      #pragma unroll
      for (int j = 0; j < 8; ++j)
        acc[i][j] = __builtin_amdgcn_mfma_f32_16x16x32_f16(a[i], bf[j], acc[i][j], 0, 0, 0);
    if (regp) {
      int cb = kn - 512 + rchunk*8;
      float4 sc0 = *(float4*)&sSc[cb], sc1 = *(float4*)&sSc[cb+4];
      float4 sh0 = *(float4*)&sSh[cb], sh1 = *(float4*)&sSh[cb+4];
      half8 v0 = *(half8*)&h0, v1 = *(half8*)&h1;
      half8 o0, o1;
      o0[0]=(f16)fmaxf((float)v0[0]*sc0.x+sh0.x, 0.f);
      o0[1]=(f16)fmaxf((float)v0[1]*sc0.y+sh0.y, 0.f);
      o0[2]=(f16)fmaxf((float)v0[2]*sc0.z+sh0.z, 0.f);
      o0[3]=(f16)fmaxf((float)v0[3]*sc0.w+sh0.w, 0.f);
      o0[4]=(f16)fmaxf((float)v0[4]*sc1.x+sh1.x, 0.f);
      o0[5]=(f16)fmaxf((float)v0[5]*sc1.y+sh1.y, 0.f);
      o0[6]=(f16)fmaxf((float)v0[6]*sc1.z+sh1.z, 0.f);
      o0[7]=(f16)fmaxf((float)v0[7]*sc1.w+sh1.w, 0.f);
      o1[0]=(f16)fmaxf((float)v1[0]*sc0.x+sh0.x, 0.f);
      o1[1]=(f16)fmaxf((float)v1[1]*sc0.y+sh0.y, 0.f);
      o1[2]=(f16)fmaxf((float)v1[2]*sc0.z+sh0.z, 0.f);
      o1[3]=(f16)fmaxf((float)v1[3]*sc0.w+sh0.w, 0.f);
      o1[4]=(f16)fmaxf((float)v1[4]*sc1.x+sh1.x, 0.f);
      o1[5]=(f16)fmaxf((float)v1[5]*sc1.y+sh1.y, 0.f);
      o1[6]=(f16)fmaxf((float)v1[6]*sc1.z+sh1.z, 0.f);
      o1[7]=(f16)fmaxf((float)v1[7]*sc1.w+sh1.w, 0.f);
      if (pad) {
        uint4 z; z.x=0u; z.y=0u; z.z=0u; z.w=0u;
        *(uint4*)&o0 = z; *(uint4*)&o1 = z;
      }
      *(uint4*)&sA[nxt][rr*32 + rslot]        = *(uint4*)&o0;
      *(uint4*)&sA[nxt][(64 + rr)*32 + rslot] = *(uint4*)&o1;
    }
    __syncthreads();
  }
  // epilogue: masked max over the 58 real rows of this wave's batch (rw)
  #pragma unroll
  for (int j = 0; j < 8; ++j) {
    float mx = -3.0e38f;
    #pragma unroll
    for (int i = 0; i < 4; ++i) {
      int rib = i*16 + quad*4;
      #pragma unroll
      for (int r = 0; r < 4; ++r)
        if (rib + r < K_) mx = fmaxf(mx, acc[i][j][r]);
    }
    mx = fmaxf(mx, __shfl_xor(mx, 16));
    mx = fmaxf(mx, __shfl_xor(mx, 32));
    if (lane < 16) sMax[w][j*16 + lm] = mx;   // wave w: batch rw, col-half cw
  }
  __syncthreads();
  #pragma unroll
  for (int bb = 0; bb < 2; ++bb) {
    int c = t;                           // 256 cols
    float mx = sMax[bb + 2*(c >> 7)][c & 127];
    int e = e0 + c;
    out[((size_t)bm*2 + bb)*E_ + e] = mx + bfc[e] + b2[e];
  }
}

extern "C" void kernel_launch(void* const* d_in, const int* in_sizes, int n_in,
                              void* d_out, int out_size, void* d_ws, size_t ws_size,
                              hipStream_t stream) {
  const float* emb   = (const float*)d_in[0];
  const float* attn  = (const float*)d_in[1];
  const float* Wfc   = (const float*)d_in[2];
  const float* bfc   = (const float*)d_in[3];
  const float* W1    = (const float*)d_in[4];
  const float* b1    = (const float*)d_in[5];
  const float* gamma = (const float*)d_in[6];
  const float* beta  = (const float*)d_in[7];
  const float* W2    = (const float*)d_in[8];
  const float* b2    = (const float*)d_in[9];
  float* out = (float*)d_out;

  char* ws = (char*)d_ws;
  f16*   A16   = (f16*)(ws);                    // 16384*1024*2 = 33,554,432
  f16*   Wcat  = (f16*)(ws + 33554432);         // 1024*1024*2  =  2,097,152
  f16*   W1_16 = (f16*)(ws + 35651584);         //  512*512*2   =    524,288
  float* csum  = (float*)(ws + 36175872);       // 2048
  float* css   = (float*)(ws + 36177920);       // 2048 (contiguous after csum)

  setup_kernel<<<897, 256, 0, stream>>>(Wfc, W2, W1, attn, emb, Wcat, W1_16, A16, csum);
  gemm1_kernel<<<256, 256, 0, stream>>>(A16, W1_16, b1, A16, csum, css);
  fused_kernel<<<512, 256, 0, stream>>>(A16, Wcat, csum, css, gamma, beta, bfc, b2, out);
}

// Round 9
// 242.403 us; speedup vs baseline: 1.3055x; 1.0042x over previous
//
#include <hip/hip_runtime.h>
#include <hip/hip_fp16.h>

#define B_ 256
#define N_ 192
#define D_ 512
#define E_ 1024
#define H_ 512
#define K_ 58
#define M_ (B_*K_)      // 14848 real rows
#define M2_ (B_*64)     // 16384 padded rows (64 per batch, rows 58-63 zero)

typedef _Float16 f16;
typedef unsigned int u32;
typedef _Float16 half8 __attribute__((ext_vector_type(8)));
typedef float floatx16 __attribute__((ext_vector_type(16)));

__device__ inline half8 cvt8(float4 f0, float4 f1) {
  half8 r;
  r[0]=(f16)f0.x; r[1]=(f16)f0.y; r[2]=(f16)f0.z; r[3]=(f16)f0.w;
  r[4]=(f16)f1.x; r[5]=(f16)f1.y; r[6]=(f16)f1.z; r[7]=(f16)f1.w;
  return r;
}

// async global->LDS, 16B/lane; LDS dest = wave-uniform base + lane*16
__device__ inline void gl_lds16(const f16* g, f16* l) {
  __builtin_amdgcn_global_load_lds((const __attribute__((address_space(1))) u32*)g,
                                   (__attribute__((address_space(3))) u32*)l, 16, 0, 0);
}

// Stage Nx32 f16 tile with XOR swizzle: LDS slot (r, c') holds global chunk
// c = c' ^ ((r>>1)&3).  Lane l covers row l>>2, slot c'=l&3, fetching global
// chunk (l&3)^((l>>3)&3).  Conflict-free (2-way max) on MFMA fragment reads.
__device__ inline void stage128(const f16* gbase, int gstride, f16* sT, int w, int lane) {
  int lrow  = lane >> 2;
  int chunk = (lane & 3) ^ ((lane >> 3) & 3);
  gl_lds16(gbase + (size_t)(w*16      + lrow)*gstride + chunk*8, &sT[(w*16)*32]);
  gl_lds16(gbase + (size_t)(64 + w*16 + lrow)*gstride + chunk*8, &sT[(64 + w*16)*32]);
}
__device__ inline void stage256(const f16* gbase, int gstride, f16* sT, int w, int lane) {
  int lrow  = lane >> 2;
  int chunk = (lane & 3) ^ ((lane >> 3) & 3);
  #pragma unroll
  for (int q = 0; q < 4; ++q)
    gl_lds16(gbase + (size_t)(q*64 + w*16 + lrow)*gstride + chunk*8, &sT[(q*64 + w*16)*32]);
}

// ---------- setup: weight cvt + topk + gather + L2norm + stats-zero ---------
__global__ void setup_kernel(const float* __restrict__ Wfc, const float* __restrict__ W2,
                             const float* __restrict__ W1, const float* __restrict__ attn,
                             const float* __restrict__ emb,
                             f16* __restrict__ Wcat, f16* __restrict__ W1_16,
                             f16* __restrict__ A16, float* __restrict__ csum) {
  __shared__ float sv[N_];
  __shared__ int sidx[K_];
  __shared__ int cnt;
  int blk = blockIdx.x, t = threadIdx.x;
  if (blk < 512) {                      // Wcat = [Wfc;W2]: 1024x1024 f16
    int idx = (blk*256 + t)*8;
    int e = idx >> 10, c = idx & 1023;
    const float* src = (c < 512) ? (Wfc + (size_t)e*512 + c)
                                 : (W2  + (size_t)e*512 + (c-512));
    half8 o = cvt8(((const float4*)src)[0], ((const float4*)src)[1]);
    *(uint4*)(Wcat + idx) = *(uint4*)&o;
  } else if (blk < 640) {               // W1_16: 512x512 f16
    int idx = ((blk-512)*256 + t)*8;
    const float* src = W1 + idx;
    half8 o = cvt8(((const float4*)src)[0], ((const float4*)src)[1]);
    *(uint4*)(W1_16 + idx) = *(uint4*)&o;
  } else if (blk < 896) {               // topk + gather + L2norm for batch b
    int b = blk - 640;
    if (t == 0) cnt = 0;
    if (t < N_) sv[t] = attn[(size_t)b*193*193 + 1 + t];
    __syncthreads();
    if (t < N_) {
      float v = sv[t]; int rank = 0;
      for (int j = 0; j < N_; ++j) {
        float vj = sv[j];
        rank += (vj > v) || (vj == v && j < t);   // lax.top_k stable tie-break
      }
      if (rank < K_) sidx[atomicAdd(&cnt, 1)] = t;  // slot order irrelevant (max/BN invariant)
    }
    __syncthreads();
    int w = t >> 6, lane = t & 63;
    for (int slot = w; slot < 64; slot += 4) {
      f16* dst = A16 + ((size_t)b*64 + slot)*1024 + lane*8;
      if (slot < K_) {
        const float* src = emb + ((size_t)b*N_ + sidx[slot])*D_ + lane*8;
        float4 v0 = ((const float4*)src)[0];
        float4 v1 = ((const float4*)src)[1];
        float s = v0.x*v0.x + v0.y*v0.y + v0.z*v0.z + v0.w*v0.w
                + v1.x*v1.x + v1.y*v1.y + v1.z*v1.z + v1.w*v1.w;
        #pragma unroll
        for (int off = 32; off > 0; off >>= 1) s += __shfl_xor(s, off);
        float inv = 1.0f / (sqrtf(s) + 1e-8f);
        half8 o;
        o[0]=(f16)(v0.x*inv); o[1]=(f16)(v0.y*inv); o[2]=(f16)(v0.z*inv); o[3]=(f16)(v0.w*inv);
        o[4]=(f16)(v1.x*inv); o[5]=(f16)(v1.y*inv); o[6]=(f16)(v1.z*inv); o[7]=(f16)(v1.w*inv);
        *(uint4*)dst = *(uint4*)&o;
      } else {
        uint4 z; z.x=0u; z.y=0u; z.z=0u; z.w=0u;
        *(uint4*)dst = z;   // pad rows zero
      }
    }
  } else {                              // zero csum(512)+css(512), contiguous
    float4 z; z.x=0.f; z.y=0.f; z.z=0.f; z.w=0.f;
    ((float4*)csum)[t] = z;
  }
}

// ---------- gemm1: A16[:,512:1024] = A16[:,0:512] @ W1_16^T + b1 + stats ----
// 128x256 tile, BK=32, dbuf LDS, 32x32x16 MFMA, XCD-swizzled grid (256 blocks).
__launch_bounds__(256, 2)
__global__ void gemm1_kernel(const f16* __restrict__ A16, const f16* __restrict__ W1_16,
                             const float* __restrict__ b1, f16* __restrict__ Aout,
                             float* __restrict__ csum, float* __restrict__ css) {
  __shared__ f16 sA[2][128*32];
  __shared__ f16 sB[2][256*32];
  __shared__ float sSum[4][128], sSS[4][128];
  int t = threadIdx.x;
  int g = blockIdx.x;                   // 256 blocks: xcd-swizzled
  int xcd = g & 7, rest = g >> 3;
  int n0 = (rest & 1) * 256;
  int m0 = (xcd + 8*(rest >> 1)) * 128; // same-m blocks same XCD
  int lane = t & 63, w = t >> 6;
  int l31 = lane & 31, khalf = lane >> 5, swz = (l31 >> 1) & 3;
  int rw = w & 1, cw = w >> 1;          // wave -> 64-row half x 128-col half
  floatx16 acc[2][4] = {};
  const f16* Ab = A16 + (size_t)m0*1024;       // left half (cols 0..511)
  const f16* Bb = W1_16 + (size_t)n0*512;
  stage128(Ab, 1024, sA[0], w, lane);
  stage256(Bb, 512,  sB[0], w, lane);
  __syncthreads();
  for (int it = 0; it < 16; ++it) {
    int cur = it & 1, nxt = cur ^ 1;
    if (it < 15) {
      stage128(Ab + (it+1)*32, 1024, sA[nxt], w, lane);
      stage256(Bb + (it+1)*32, 512,  sB[nxt], w, lane);
    }
    #pragma unroll
    for (int s = 0; s < 2; ++s) {       // two K=16 steps per 32-wide buffer
      int ko = ((s*2 + khalf) ^ swz) * 8;
      half8 a[2], bf[4];
      #pragma unroll
      for (int i = 0; i < 2; ++i) a[i]  = *(const half8*)&sA[cur][(rw*64  + i*32 + l31)*32 + ko];
      #pragma unroll
      for (int j = 0; j < 4; ++j) bf[j] = *(const half8*)&sB[cur][(cw*128 + j*32 + l31)*32 + ko];
      #pragma unroll
      for (int i = 0; i < 2; ++i)
        #pragma unroll
        for (int j = 0; j < 4; ++j)
          acc[i][j] = __builtin_amdgcn_mfma_f32_32x32x16_f16(a[i], bf[j], acc[i][j], 0, 0, 0);
    }
    __syncthreads();
  }
  // epilogue: write pre-BN h into A16 right half, masked column stats
  // C/D: col = l31, row = (reg&3) + 8*(reg>>2) + 4*khalf  (within 32x32 tile)
  #pragma unroll
  for (int jt = 0; jt < 4; ++jt) {
    int col = n0 + cw*128 + jt*32 + l31;
    float bias = b1[col];
    float s = 0.f, ss = 0.f;
    #pragma unroll
    for (int i = 0; i < 2; ++i) {
      #pragma unroll
      for (int rg = 0; rg < 16; ++rg) {
        int rib = i*32 + (rg&3) + 8*(rg>>2) + 4*khalf;   // row within batch (0..63)
        float x = acc[i][jt][rg] + bias;
        Aout[(size_t)(m0 + rw*64 + rib)*1024 + 512 + col] = (f16)x;
        if (i == 0 || rib < K_) { s += x; ss += x*x; }
      }
    }
    s  += __shfl_xor(s, 32);
    ss += __shfl_xor(ss, 32);
    if (lane < 32) { sSum[w][jt*32 + l31] = s; sSS[w][jt*32 + l31] = ss; }
  }
  __syncthreads();
  {
    int c = t;                          // 256 cols in this block
    int w0 = 2*(c >> 7), ci = c & 127;  // waves rw=0/1 of this col-half
    atomicAdd(&csum[n0 + c], sSum[w0][ci] + sSum[w0+1][ci]);
    atomicAdd(&css[n0 + c],  sSS[w0][ci]  + sSS[w0+1][ci]);
  }
}

// ---------- fused: C = [base ; relu(bn(h))] @ Wcat^T, max over k, + biases ---
// 128x256 tile (2 batches x 256 e), BK=32, dbuf, 32x32x16 MFMA, XCD-swizzled.
// A left half + B: global_load_lds.  A right half: regs -> BN+relu -> ds_write.
__launch_bounds__(256, 2)
__global__ void fused_kernel(const f16* __restrict__ A16, const f16* __restrict__ Wcat,
                             const float* __restrict__ csum, const float* __restrict__ css,
                             const float* __restrict__ gamma, const float* __restrict__ beta,
                             const float* __restrict__ bfc, const float* __restrict__ b2,
                             float* __restrict__ out) {
  __shared__ f16 sA[2][128*32];
  __shared__ f16 sB[2][256*32];
  __shared__ float sSc[H_], sSh[H_];
  __shared__ float sMax[4][128];
  int t = threadIdx.x;
  int g = blockIdx.x;                   // 512 blocks: xcd-swizzled
  int xcd = g & 7, rest = g >> 3;
  int e0 = (rest & 3) * 256;
  int bm = xcd + 8*(rest >> 2);         // batch-pair 0..127; same-bm blocks same XCD
  int lane = t & 63, w = t >> 6;
  int l31 = lane & 31, khalf = lane >> 5, swz = (l31 >> 1) & 3;
  int rw = w & 1, cw = w >> 1;
  // BN scale/shift from gemm1's global stats
  #pragma unroll
  for (int jj = 0; jj < 2; ++jj) {
    int j = t + jj*256;
    float mu  = csum[j] * (1.0f/M_);
    float var = css[j] * (1.0f/M_) - mu*mu;
    float sc  = gamma[j] * rsqrtf(var + 1e-5f);
    sSc[j] = sc;
    sSh[j] = beta[j] - mu*sc;
  }
  floatx16 acc[2][4] = {};
  const f16* Ab = A16 + (size_t)bm*128*1024;
  const f16* Bb = Wcat + (size_t)e0*1024;
  // reg-path (A right half) constants: thread t covers rows t>>2 and 64+(t>>2),
  // LDS slot c'=t&3, global chunk (t&3)^((t>>3)&3)  [slot holds chunk c'^((r>>1)&3)]
  int rr = t >> 2;
  int rslot  = (t & 3) * 8;
  int rchunk = (t & 3) ^ ((t >> 3) & 3);
  bool pad = (rr >= K_);
  stage128(Ab, 1024, sA[0], w, lane);
  stage256(Bb, 1024, sB[0], w, lane);
  __syncthreads();                      // also guards sSc/sSh
  for (int it = 0; it < 32; ++it) {
    int cur = it & 1, nxt = cur ^ 1;
    int kn = (it + 1) * 32;
    uint4 h0, h1;
    bool regp = false;
    if (it < 31) {
      stage256(Bb + kn, 1024, sB[nxt], w, lane);
      if (kn < 512) {
        stage128(Ab + kn, 1024, sA[nxt], w, lane);
      } else {                          // plain loads now; BN+ds_write after compute
        regp = true;
        const f16* hp = Ab + (size_t)rr*1024 + kn + rchunk*8;
        h0 = *(const uint4*)hp;
        h1 = *(const uint4*)(hp + (size_t)64*1024);
      }
    }
    #pragma unroll
    for (int s = 0; s < 2; ++s) {
      int ko = ((s*2 + khalf) ^ swz) * 8;
      half8 a[2], bf[4];
      #pragma unroll
      for (int i = 0; i < 2; ++i) a[i]  = *(const half8*)&sA[cur][(rw*64  + i*32 + l31)*32 + ko];
      #pragma unroll
      for (int j = 0; j < 4; ++j) bf[j] = *(const half8*)&sB[cur][(cw*128 + j*32 + l31)*32 + ko];
      #pragma unroll
      for (int i = 0; i < 2; ++i)
        #pragma unroll
        for (int j = 0; j < 4; ++j)
          acc[i][j] = __builtin_amdgcn_mfma_f32_32x32x16_f16(a[i], bf[j], acc[i][j], 0, 0, 0);
    }
    if (regp) {
      int cb = kn - 512 + rchunk*8;
      float4 sc0 = *(float4*)&sSc[cb], sc1 = *(float4*)&sSc[cb+4];
      float4 sh0 = *(float4*)&sSh[cb], sh1 = *(float4*)&sSh[cb+4];
      half8 v0 = *(half8*)&h0, v1 = *(half8*)&h1;
      half8 o0, o1;
      o0[0]=(f16)fmaxf((float)v0[0]*sc0.x+sh0.x, 0.f);
      o0[1]=(f16)fmaxf((float)v0[1]*sc0.y+sh0.y, 0.f);
      o0[2]=(f16)fmaxf((float)v0[2]*sc0.z+sh0.z, 0.f);
      o0[3]=(f16)fmaxf((float)v0[3]*sc0.w+sh0.w, 0.f);
      o0[4]=(f16)fmaxf((float)v0[4]*sc1.x+sh1.x, 0.f);
      o0[5]=(f16)fmaxf((float)v0[5]*sc1.y+sh1.y, 0.f);
      o0[6]=(f16)fmaxf((float)v0[6]*sc1.z+sh1.z, 0.f);
      o0[7]=(f16)fmaxf((float)v0[7]*sc1.w+sh1.w, 0.f);
      o1[0]=(f16)fmaxf((float)v1[0]*sc0.x+sh0.x, 0.f);
      o1[1]=(f16)fmaxf((float)v1[1]*sc0.y+sh0.y, 0.f);
      o1[2]=(f16)fmaxf((float)v1[2]*sc0.z+sh0.z, 0.f);
      o1[3]=(f16)fmaxf((float)v1[3]*sc0.w+sh0.w, 0.f);
      o1[4]=(f16)fmaxf((float)v1[4]*sc1.x+sh1.x, 0.f);
      o1[5]=(f16)fmaxf((float)v1[5]*sc1.y+sh1.y, 0.f);
      o1[6]=(f16)fmaxf((float)v1[6]*sc1.z+sh1.z, 0.f);
      o1[7]=(f16)fmaxf((float)v1[7]*sc1.w+sh1.w, 0.f);
      if (pad) {
        uint4 z; z.x=0u; z.y=0u; z.z=0u; z.w=0u;
        *(uint4*)&o0 = z; *(uint4*)&o1 = z;
      }
      *(uint4*)&sA[nxt][rr*32 + rslot]        = *(uint4*)&o0;
      *(uint4*)&sA[nxt][(64 + rr)*32 + rslot] = *(uint4*)&o1;
    }
    __syncthreads();
  }
  // epilogue: masked max over the 58 real rows of this wave's batch (rw)
  #pragma unroll
  for (int jt = 0; jt < 4; ++jt) {
    float mx = -3.0e38f;
    #pragma unroll
    for (int i = 0; i < 2; ++i) {
      #pragma unroll
      for (int rg = 0; rg < 16; ++rg) {
        int rib = i*32 + (rg&3) + 8*(rg>>2) + 4*khalf;
        if (i == 0 || rib < K_) mx = fmaxf(mx, acc[i][jt][rg]);
      }
    }
    mx = fmaxf(mx, __shfl_xor(mx, 32));
    if (lane < 32) sMax[w][jt*32 + l31] = mx;   // wave w: batch rw, col-half cw
  }
  __syncthreads();
  #pragma unroll
  for (int bb = 0; bb < 2; ++bb) {
    int c = t;                           // 256 cols
    float mx = sMax[bb + 2*(c >> 7)][c & 127];
    int e = e0 + c;
    out[((size_t)bm*2 + bb)*E_ + e] = mx + bfc[e] + b2[e];
  }
}

extern "C" void kernel_launch(void* const* d_in, const int* in_sizes, int n_in,
                              void* d_out, int out_size, void* d_ws, size_t ws_size,
                              hipStream_t stream) {
  const float* emb   = (const float*)d_in[0];
  const float* attn  = (const float*)d_in[1];
  const float* Wfc   = (const float*)d_in[2];
  const float* bfc   = (const float*)d_in[3];
  const float* W1    = (const float*)d_in[4];
  const float* b1    = (const float*)d_in[5];
  const float* gamma = (const float*)d_in[6];
  const float* beta  = (const float*)d_in[7];
  const float* W2    = (const float*)d_in[8];
  const float* b2    = (const float*)d_in[9];
  float* out = (float*)d_out;

  char* ws = (char*)d_ws;
  f16*   A16   = (f16*)(ws);                    // 16384*1024*2 = 33,554,432
  f16*   Wcat  = (f16*)(ws + 33554432);         // 1024*1024*2  =  2,097,152
  f16*   W1_16 = (f16*)(ws + 35651584);         //  512*512*2   =    524,288
  float* csum  = (float*)(ws + 36175872);       // 2048
  float* css   = (float*)(ws + 36177920);       // 2048 (contiguous after csum)

  setup_kernel<<<897, 256, 0, stream>>>(Wfc, W2, W1, attn, emb, Wcat, W1_16, A16, csum);
  gemm1_kernel<<<256, 256, 0, stream>>>(A16, W1_16, b1, A16, csum, css);
  fused_kernel<<<512, 256, 0, stream>>>(A16, Wcat, csum, css, gamma, beta, bfc, b2, out);
}

// Round 10
// 239.238 us; speedup vs baseline: 1.3228x; 1.0132x over previous
//
#include <hip/hip_runtime.h>
#include <hip/hip_fp16.h>

#define B_ 256
#define N_ 192
#define D_ 512
#define E_ 1024
#define H_ 512
#define K_ 58
#define M_ (B_*K_)      // 14848 real rows
#define M2_ (B_*64)     // 16384 padded rows (64 per batch, rows 58-63 zero)

typedef _Float16 f16;
typedef unsigned int u32;
typedef _Float16 half8 __attribute__((ext_vector_type(8)));
typedef float floatx16 __attribute__((ext_vector_type(16)));

__device__ inline half8 cvt8(float4 f0, float4 f1) {
  half8 r;
  r[0]=(f16)f0.x; r[1]=(f16)f0.y; r[2]=(f16)f0.z; r[3]=(f16)f0.w;
  r[4]=(f16)f1.x; r[5]=(f16)f1.y; r[6]=(f16)f1.z; r[7]=(f16)f1.w;
  return r;
}

// async global->LDS, 16B/lane; LDS dest = wave-uniform base + lane*16
__device__ inline void gl_lds16(const f16* g, f16* l) {
  __builtin_amdgcn_global_load_lds((const __attribute__((address_space(1))) u32*)g,
                                   (__attribute__((address_space(3))) u32*)l, 16, 0, 0);
}

// Stage 128x32 f16 tile with XOR swizzle: LDS slot (r, c') holds global chunk
// c = c' ^ ((r>>1)&3).  Lane l covers row l>>2, slot c'=l&3, fetching global
// chunk (l&3)^((l>>3)&3).  Conflict-free (2-way max) on MFMA fragment reads.
__device__ inline void stage128(const f16* gbase, int gstride, f16* sT, int w, int lane) {
  int lrow  = lane >> 2;
  int chunk = (lane & 3) ^ ((lane >> 3) & 3);
  gl_lds16(gbase + (size_t)(w*16      + lrow)*gstride + chunk*8, &sT[(w*16)*32]);
  gl_lds16(gbase + (size_t)(64 + w*16 + lrow)*gstride + chunk*8, &sT[(64 + w*16)*32]);
}

// ---------- setup: weight cvt + topk + gather + L2norm + stats-zero ---------
__global__ void setup_kernel(const float* __restrict__ Wfc, const float* __restrict__ W2,
                             const float* __restrict__ W1, const float* __restrict__ attn,
                             const float* __restrict__ emb,
                             f16* __restrict__ Wcat, f16* __restrict__ W1_16,
                             f16* __restrict__ A16, float* __restrict__ csum) {
  __shared__ float sv[N_];
  __shared__ int sidx[K_];
  __shared__ int cnt;
  int blk = blockIdx.x, t = threadIdx.x;
  if (blk < 512) {                      // Wcat = [Wfc;W2]: 1024x1024 f16
    int idx = (blk*256 + t)*8;
    int e = idx >> 10, c = idx & 1023;
    const float* src = (c < 512) ? (Wfc + (size_t)e*512 + c)
                                 : (W2  + (size_t)e*512 + (c-512));
    half8 o = cvt8(((const float4*)src)[0], ((const float4*)src)[1]);
    *(uint4*)(Wcat + idx) = *(uint4*)&o;
  } else if (blk < 640) {               // W1_16: 512x512 f16
    int idx = ((blk-512)*256 + t)*8;
    const float* src = W1 + idx;
    half8 o = cvt8(((const float4*)src)[0], ((const float4*)src)[1]);
    *(uint4*)(W1_16 + idx) = *(uint4*)&o;
  } else if (blk < 896) {               // topk + gather + L2norm for batch b
    int b = blk - 640;
    if (t == 0) cnt = 0;
    if (t < N_) sv[t] = attn[(size_t)b*193*193 + 1 + t];
    __syncthreads();
    if (t < N_) {
      float v = sv[t]; int rank = 0;
      for (int j = 0; j < N_; ++j) {
        float vj = sv[j];
        rank += (vj > v) || (vj == v && j < t);   // lax.top_k stable tie-break
      }
      if (rank < K_) sidx[atomicAdd(&cnt, 1)] = t;  // slot order irrelevant (max/BN invariant)
    }
    __syncthreads();
    int w = t >> 6, lane = t & 63;
    for (int slot = w; slot < 64; slot += 4) {
      f16* dst = A16 + ((size_t)b*64 + slot)*1024 + lane*8;
      if (slot < K_) {
        const float* src = emb + ((size_t)b*N_ + sidx[slot])*D_ + lane*8;
        float4 v0 = ((const float4*)src)[0];
        float4 v1 = ((const float4*)src)[1];
        float s = v0.x*v0.x + v0.y*v0.y + v0.z*v0.z + v0.w*v0.w
                + v1.x*v1.x + v1.y*v1.y + v1.z*v1.z + v1.w*v1.w;
        #pragma unroll
        for (int off = 32; off > 0; off >>= 1) s += __shfl_xor(s, off);
        float inv = 1.0f / (sqrtf(s) + 1e-8f);
        half8 o;
        o[0]=(f16)(v0.x*inv); o[1]=(f16)(v0.y*inv); o[2]=(f16)(v0.z*inv); o[3]=(f16)(v0.w*inv);
        o[4]=(f16)(v1.x*inv); o[5]=(f16)(v1.y*inv); o[6]=(f16)(v1.z*inv); o[7]=(f16)(v1.w*inv);
        *(uint4*)dst = *(uint4*)&o;
      } else {
        uint4 z; z.x=0u; z.y=0u; z.z=0u; z.w=0u;
        *(uint4*)dst = z;   // pad rows zero
      }
    }
  } else {                              // zero csum(512)+css(512), contiguous
    float4 z; z.x=0.f; z.y=0.f; z.z=0.f; z.w=0.f;
    ((float4*)csum)[t] = z;
  }
}

// ---------- gemm1: A16[:,512:1024] = A16[:,0:512] @ W1_16^T + b1 + stats ----
// 128x128 tile, BK=32, dbuf LDS, 32x32x16 MFMA, XCD-swizzled grid (512 blocks).
__launch_bounds__(256, 2)
__global__ void gemm1_kernel(const f16* __restrict__ A16, const f16* __restrict__ W1_16,
                             const float* __restrict__ b1, f16* __restrict__ Aout,
                             float* __restrict__ csum, float* __restrict__ css) {
  __shared__ f16 sA[2][128*32];
  __shared__ f16 sB[2][128*32];
  __shared__ float sSum[4][64], sSS[4][64];
  int t = threadIdx.x;
  int g = blockIdx.x;                   // 512 blocks: xcd-swizzled
  int xcd = g & 7, rest = g >> 3;
  int n0 = (rest & 3) * 128;            // 4 n-tiles
  int m0 = (xcd + 8*(rest >> 2)) * 128; // same-m blocks same XCD
  int lane = t & 63, w = t >> 6;
  int l31 = lane & 31, khalf = lane >> 5, swz = (l31 >> 1) & 3;
  int rw = w & 1, cw = w >> 1;          // wave -> 64-row half x 64-col half
  floatx16 acc[2][2] = {};
  const f16* Ab = A16 + (size_t)m0*1024;       // left half (cols 0..511)
  const f16* Bb = W1_16 + (size_t)n0*512;
  stage128(Ab, 1024, sA[0], w, lane);
  stage128(Bb, 512,  sB[0], w, lane);
  __syncthreads();
  for (int it = 0; it < 16; ++it) {
    int cur = it & 1, nxt = cur ^ 1;
    if (it < 15) {
      stage128(Ab + (it+1)*32, 1024, sA[nxt], w, lane);
      stage128(Bb + (it+1)*32, 512,  sB[nxt], w, lane);
    }
    #pragma unroll
    for (int s = 0; s < 2; ++s) {       // two K=16 steps per 32-wide buffer
      int ko = ((s*2 + khalf) ^ swz) * 8;
      half8 a[2], bf[2];
      #pragma unroll
      for (int i = 0; i < 2; ++i) a[i]  = *(const half8*)&sA[cur][(rw*64 + i*32 + l31)*32 + ko];
      #pragma unroll
      for (int j = 0; j < 2; ++j) bf[j] = *(const half8*)&sB[cur][(cw*64 + j*32 + l31)*32 + ko];
      #pragma unroll
      for (int i = 0; i < 2; ++i)
        #pragma unroll
        for (int j = 0; j < 2; ++j)
          acc[i][j] = __builtin_amdgcn_mfma_f32_32x32x16_f16(a[i], bf[j], acc[i][j], 0, 0, 0);
    }
    __syncthreads();
  }
  // epilogue: write pre-BN h into A16 right half, masked column stats
  // C/D: col = l31, row = (reg&3) + 8*(reg>>2) + 4*khalf  (within 32x32 tile)
  #pragma unroll
  for (int jt = 0; jt < 2; ++jt) {
    int col = n0 + cw*64 + jt*32 + l31;
    float bias = b1[col];
    float s = 0.f, ss = 0.f;
    #pragma unroll
    for (int i = 0; i < 2; ++i) {
      #pragma unroll
      for (int rg = 0; rg < 16; ++rg) {
        int rib = i*32 + (rg&3) + 8*(rg>>2) + 4*khalf;   // row within batch (0..63)
        float x = acc[i][jt][rg] + bias;
        Aout[(size_t)(m0 + rw*64 + rib)*1024 + 512 + col] = (f16)x;
        if (i == 0 || rib < K_) { s += x; ss += x*x; }
      }
    }
    s  += __shfl_xor(s, 32);
    ss += __shfl_xor(ss, 32);
    if (lane < 32) { sSum[w][jt*32 + l31] = s; sSS[w][jt*32 + l31] = ss; }
  }
  __syncthreads();
  if (t < 128) {
    int c = t;                          // 128 cols in this block
    int w0 = 2*(c >> 6), ci = c & 63;   // waves rw=0/1 of this col-half
    atomicAdd(&csum[n0 + c], sSum[w0][ci] + sSum[w0+1][ci]);
    atomicAdd(&css[n0 + c],  sSS[w0][ci]  + sSS[w0+1][ci]);
  }
}

// ---------- fused: C = [base ; relu(bn(h))] @ Wcat^T, max over k, + biases ---
// 128x128 tile (2 batches x 128 e), BK=32, dbuf, 32x32x16 MFMA, XCD-swizzled
// grid (1024 blocks, 3/CU).  A left half + B: global_load_lds.  A right half:
// regs -> BN+relu -> ds_write (same swizzled layout; pad rows zeroed).
__launch_bounds__(256, 3)
__global__ void fused_kernel(const f16* __restrict__ A16, const f16* __restrict__ Wcat,
                             const float* __restrict__ csum, const float* __restrict__ css,
                             const float* __restrict__ gamma, const float* __restrict__ beta,
                             const float* __restrict__ bfc, const float* __restrict__ b2,
                             float* __restrict__ out) {
  __shared__ f16 sA[2][128*32];
  __shared__ f16 sB[2][128*32];
  __shared__ float sSc[H_], sSh[H_];
  __shared__ float sMax[4][64];
  int t = threadIdx.x;
  int g = blockIdx.x;                   // 1024 blocks: xcd-swizzled
  int xcd = g & 7, rest = g >> 3;
  int e0 = (rest & 7) * 128;            // 8 e-tiles
  int bm = xcd + 8*(rest >> 3);         // batch-pair 0..127; same-bm blocks same XCD
  int lane = t & 63, w = t >> 6;
  int l31 = lane & 31, khalf = lane >> 5, swz = (l31 >> 1) & 3;
  int rw = w & 1, cw = w >> 1;
  // BN scale/shift from gemm1's global stats
  #pragma unroll
  for (int jj = 0; jj < 2; ++jj) {
    int j = t + jj*256;
    float mu  = csum[j] * (1.0f/M_);
    float var = css[j] * (1.0f/M_) - mu*mu;
    float sc  = gamma[j] * rsqrtf(var + 1e-5f);
    sSc[j] = sc;
    sSh[j] = beta[j] - mu*sc;
  }
  floatx16 acc[2][2] = {};
  const f16* Ab = A16 + (size_t)bm*128*1024;
  const f16* Bb = Wcat + (size_t)e0*1024;
  // reg-path (A right half): thread t covers rows t>>2 and 64+(t>>2),
  // LDS slot c'=t&3, global chunk (t&3)^((t>>3)&3)  [slot holds chunk c'^((r>>1)&3)]
  int rr = t >> 2;
  int rslot  = (t & 3) * 8;
  int rchunk = (t & 3) ^ ((t >> 3) & 3);
  bool pad = (rr >= K_);
  stage128(Ab, 1024, sA[0], w, lane);
  stage128(Bb, 1024, sB[0], w, lane);
  __syncthreads();                      // also guards sSc/sSh
  for (int it = 0; it < 32; ++it) {
    int cur = it & 1, nxt = cur ^ 1;
    int kn = (it + 1) * 32;
    uint4 h0, h1;
    bool regp = false;
    if (it < 31) {
      stage128(Bb + kn, 1024, sB[nxt], w, lane);
      if (kn < 512) {
        stage128(Ab + kn, 1024, sA[nxt], w, lane);
      } else {                          // plain loads now; BN+ds_write after compute
        regp = true;
        const f16* hp = Ab + (size_t)rr*1024 + kn + rchunk*8;
        h0 = *(const uint4*)hp;
        h1 = *(const uint4*)(hp + (size_t)64*1024);
      }
    }
    #pragma unroll
    for (int s = 0; s < 2; ++s) {
      int ko = ((s*2 + khalf) ^ swz) * 8;
      half8 a[2], bf[2];
      #pragma unroll
      for (int i = 0; i < 2; ++i) a[i]  = *(const half8*)&sA[cur][(rw*64 + i*32 + l31)*32 + ko];
      #pragma unroll
      for (int j = 0; j < 2; ++j) bf[j] = *(const half8*)&sB[cur][(cw*64 + j*32 + l31)*32 + ko];
      #pragma unroll
      for (int i = 0; i < 2; ++i)
        #pragma unroll
        for (int j = 0; j < 2; ++j)
          acc[i][j] = __builtin_amdgcn_mfma_f32_32x32x16_f16(a[i], bf[j], acc[i][j], 0, 0, 0);
    }
    if (regp) {
      int cb = kn - 512 + rchunk*8;
      float4 sc0 = *(float4*)&sSc[cb], sc1 = *(float4*)&sSc[cb+4];
      float4 sh0 = *(float4*)&sSh[cb], sh1 = *(float4*)&sSh[cb+4];
      half8 v0 = *(half8*)&h0, v1 = *(half8*)&h1;
      half8 o0, o1;
      o0[0]=(f16)fmaxf((float)v0[0]*sc0.x+sh0.x, 0.f);
      o0[1]=(f16)fmaxf((float)v0[1]*sc0.y+sh0.y, 0.f);
      o0[2]=(f16)fmaxf((float)v0[2]*sc0.z+sh0.z, 0.f);
      o0[3]=(f16)fmaxf((float)v0[3]*sc0.w+sh0.w, 0.f);
      o0[4]=(f16)fmaxf((float)v0[4]*sc1.x+sh1.x, 0.f);
      o0[5]=(f16)fmaxf((float)v0[5]*sc1.y+sh1.y, 0.f);
      o0[6]=(f16)fmaxf((float)v0[6]*sc1.z+sh1.z, 0.f);
      o0[7]=(f16)fmaxf((float)v0[7]*sc1.w+sh1.w, 0.f);
      o1[0]=(f16)fmaxf((float)v1[0]*sc0.x+sh0.x, 0.f);
      o1[1]=(f16)fmaxf((float)v1[1]*sc0.y+sh0.y, 0.f);
      o1[2]=(f16)fmaxf((float)v1[2]*sc0.z+sh0.z, 0.f);
      o1[3]=(f16)fmaxf((float)v1[3]*sc0.w+sh0.w, 0.f);
      o1[4]=(f16)fmaxf((float)v1[4]*sc1.x+sh1.x, 0.f);
      o1[5]=(f16)fmaxf((float)v1[5]*sc1.y+sh1.y, 0.f);
      o1[6]=(f16)fmaxf((float)v1[6]*sc1.z+sh1.z, 0.f);
      o1[7]=(f16)fmaxf((float)v1[7]*sc1.w+sh1.w, 0.f);
      if (pad) {
        uint4 z; z.x=0u; z.y=0u; z.z=0u; z.w=0u;
        *(uint4*)&o0 = z; *(uint4*)&o1 = z;
      }
      *(uint4*)&sA[nxt][rr*32 + rslot]        = *(uint4*)&o0;
      *(uint4*)&sA[nxt][(64 + rr)*32 + rslot] = *(uint4*)&o1;
    }
    __syncthreads();
  }
  // epilogue: masked max over the 58 real rows of this wave's batch (rw)
  #pragma unroll
  for (int jt = 0; jt < 2; ++jt) {
    float mx = -3.0e38f;
    #pragma unroll
    for (int i = 0; i < 2; ++i) {
      #pragma unroll
      for (int rg = 0; rg < 16; ++rg) {
        int rib = i*32 + (rg&3) + 8*(rg>>2) + 4*khalf;
        if (i == 0 || rib < K_) mx = fmaxf(mx, acc[i][jt][rg]);
      }
    }
    mx = fmaxf(mx, __shfl_xor(mx, 32));
    if (lane < 32) sMax[w][jt*32 + l31] = mx;   // wave w: batch rw, col-half cw
  }
  __syncthreads();
  #pragma unroll
  for (int bb = 0; bb < 2; ++bb) {
    int c = t & 127;                     // 128 cols; t>=128 duplicates harmlessly avoided:
    if ((t >> 7) == bb) {
      float mx = sMax[bb + 2*(c >> 6)][c & 63];
      int e = e0 + c;
      out[((size_t)bm*2 + bb)*E_ + e] = mx + bfc[e] + b2[e];
    }
  }
}

extern "C" void kernel_launch(void* const* d_in, const int* in_sizes, int n_in,
                              void* d_out, int out_size, void* d_ws, size_t ws_size,
                              hipStream_t stream) {
  const float* emb   = (const float*)d_in[0];
  const float* attn  = (const float*)d_in[1];
  const float* Wfc   = (const float*)d_in[2];
  const float* bfc   = (const float*)d_in[3];
  const float* W1    = (const float*)d_in[4];
  const float* b1    = (const float*)d_in[5];
  const float* gamma = (const float*)d_in[6];
  const float* beta  = (const float*)d_in[7];
  const float* W2    = (const float*)d_in[8];
  const float* b2    = (const float*)d_in[9];
  float* out = (float*)d_out;

  char* ws = (char*)d_ws;
  f16*   A16   = (f16*)(ws);                    // 16384*1024*2 = 33,554,432
  f16*   Wcat  = (f16*)(ws + 33554432);         // 1024*1024*2  =  2,097,152
  f16*   W1_16 = (f16*)(ws + 35651584);         //  512*512*2   =    524,288
  float* csum  = (float*)(ws + 36175872);       // 2048
  float* css   = (float*)(ws + 36177920);       // 2048 (contiguous after csum)

  setup_kernel<<<897, 256, 0, stream>>>(Wfc, W2, W1, attn, emb, Wcat, W1_16, A16, csum);
  gemm1_kernel<<<512, 256, 0, stream>>>(A16, W1_16, b1, A16, csum, css);
  fused_kernel<<<1024, 256, 0, stream>>>(A16, Wcat, csum, css, gamma, beta, bfc, b2, out);
}